// Round 6
// baseline (23472.781 us; speedup 1.0000x reference)
//
#include <hip/hip_runtime.h>
#include <math.h>

// ---------------------------------------------------------------------------
// MIM RNN round 5: conflict-free LDS B-layout [half][row][slot][col] +
// dy-blocked inner loop (120 MFMA / 16 B-reads). Split-bf16 accuracy.
// ---------------------------------------------------------------------------

#define S 524288  // 8*64*1024

typedef __attribute__((ext_vector_type(8))) short bf16x8;
typedef __attribute__((ext_vector_type(16))) float f32x16;

__device__ __forceinline__ float sigf(float x) { return 1.0f / (1.0f + expf(-x)); }
__device__ __forceinline__ unsigned short f2bf(float f) {
  unsigned u = __float_as_uint(f);
  u += 0x7fffu + ((u >> 16) & 1u);
  return (unsigned short)(u >> 16);
}
__device__ __forceinline__ float bf2f(unsigned short h) {
  return __uint_as_float(((unsigned)h) << 16);
}

struct Job {
  const float* x0; const unsigned short* w0; int cin0;
  const float* x1; const unsigned short* w1; int cin1;
  int taps; float* out; int outCo; int coBase; int coCnt; int blockStart;
};
struct Batch { Job j[10]; int n; };

// ---------------------------------------------------------------------------
// Weight prepack: W'[half][tap][ks][coB4][lane64][8] bf16.
__global__ void pack_k(unsigned short* dst, const float* src, int srcRow0,
                       int nRows, int dstRow0, int ciBase, int cinSrc, int taps,
                       int KS) {
  int idx = blockIdx.x * 256 + threadIdx.x;
  int total = taps * KS * 4 * 64;
  if (idx >= total) return;
  int l = idx & 63;
  int cb = (idx >> 6) & 3;
  int rest = idx >> 8;
  int ks = rest % KS, tap = rest / KS;
  int co_d = cb * 32 + (l & 31);
  if (co_d < dstRow0 || co_d >= dstRow0 + nRows) return;
  int srcRow = srcRow0 + (co_d - dstRow0);
  size_t AH = (size_t)taps * KS * 2048;
  size_t base = ((size_t)(tap * KS + ks) * 4 + cb) * 512 + (size_t)l * 8;
#pragma unroll
  for (int j = 0; j < 8; ++j) {
    int ci = ciBase + ks * 16 + (l >> 5) * 8 + j;
    float v = src[((size_t)srcRow * cinSrc + ci) * taps + tap];
    unsigned short hi = f2bf(v);
    unsigned short lo = f2bf(v - bf2f(hi));
    dst[base + j] = hi;
    dst[AH + base + j] = lo;
  }
}

__global__ void tr1_k(const float* __restrict__ src, float* __restrict__ dst,
                      int Cin, int Cout) {
  int idx = blockIdx.x * 256 + threadIdx.x;
  if (idx >= Cout * Cin) return;
  int ci = idx % Cin, co = idx / Cin;
  dst[(size_t)ci * Cout + co] = src[idx];
}

// ---------------------------------------------------------------------------
// Conv: block = 128co x 256px (8 img rows), 4 waves = 2 wc x 2 wr.
// LDS B-tile: [half][12 rows][4 slots][36 cols x 16B]; slot s of (row,col)
// holds ci s*8..s*8+7 (bf16). Reads are contiguous 512B per lane-group ->
// bank-conflict-free. Inner loop blocks over dy: 8 B-frags serve 5 taps.
__global__ __launch_bounds__(256, 2) void convmf4_k(Batch bt) {
  int blk = blockIdx.x;
  int ji = 0;
#pragma unroll
  for (int q = 1; q < 10; ++q)
    if (q < bt.n && blk >= bt.j[q].blockStart) ji = q;
  Job J = bt.j[ji];
  int local = blk - J.blockStart;
  int pxg = local & 3;
  int b = local >> 2;
  int r0 = pxg * 8;
  int tid = threadIdx.x, l = tid & 63, wv = tid >> 6;
  int wc = wv & 1, wr = wv >> 1;
  int lcol = l & 31, lg = l >> 5;

  __shared__ __align__(16) unsigned char lds[2][12][2304];
  unsigned char* ldsb = &lds[0][0][0];

  f32x16 acc[2][4];
#pragma unroll
  for (int r = 0; r < 2; ++r)
#pragma unroll
    for (int j2 = 0; j2 < 4; ++j2)
#pragma unroll
      for (int q = 0; q < 16; ++q) acc[r][j2][q] = 0.f;

  {  // zero halo cols 0,1,34,35 (all rows, slots, halves) once
    int e = tid;
#pragma unroll
    for (int it = 0; it < 2; ++it, e += 256)
      if (e < 384) {
        int hh = e & 1, sl = (e >> 1) & 3;
        int rq = e >> 3;  // 0..47
        int row = rq % 12, cq = rq / 12;
        int col = cq < 2 ? cq : 32 + cq;
        float4 z = {0.f, 0.f, 0.f, 0.f};
        *(float4*)(ldsb + hh * 27648 + row * 2304 + sl * 576 + col * 16) = z;
      }
  }

  for (int s = 0; s < 2; ++s) {
    const float* X = s ? J.x1 : J.x0;
    const unsigned short* W = s ? J.w1 : J.w0;
    int cin = s ? J.cin1 : J.cin0;
    if (cin == 0) continue;
    int KS = cin >> 4;
    size_t AH = (size_t)J.taps * KS * 2048;
    int nst = (cin + 31) >> 5;
    for (int st = 0; st < nst; ++st) {
      int ciCnt = cin - st * 32;
      if (ciCnt > 32) ciCnt = 32;
      int kls = ciCnt >> 4;  // 1 or 2
      __syncthreads();
      // stage 12 rows (r0-2 .. r0+9) of up-to-32 ci, hi+lo halves
      for (int u = tid; u < 1536; u += 256) {
        int cp = u & 15;
        int xq = (u >> 4) & 7;
        int row = u >> 7;  // 0..11
        if (2 * cp < ciCnt) {
          int gy = r0 - 2 + row;
          float4 v0 = {0.f, 0.f, 0.f, 0.f}, v1 = {0.f, 0.f, 0.f, 0.f};
          if ((unsigned)gy < 32u) {
            const float* p0 =
                X + (((size_t)b * cin + st * 32 + 2 * cp) << 10) + gy * 32 + xq * 4;
            v0 = *(const float4*)p0;
            v1 = *(const float4*)(p0 + 1024);
          }
          const float* e0 = (const float*)&v0;
          const float* e1 = (const float*)&v1;
          int base0 = row * 2304 + (cp >> 2) * 576 + (cp & 3) * 4;
#pragma unroll
          for (int e = 0; e < 4; ++e) {
            int off2 = base0 + (xq * 4 + 2 + e) * 16;
            unsigned short h0 = f2bf(e0[e]);
            unsigned short h1 = f2bf(e1[e]);
            unsigned short lo0 = f2bf(e0[e] - bf2f(h0));
            unsigned short lo1 = f2bf(e1[e] - bf2f(h1));
            *(unsigned*)(ldsb + off2) = (unsigned)h0 | ((unsigned)h1 << 16);
            *(unsigned*)(ldsb + 27648 + off2) = (unsigned)lo0 | ((unsigned)lo1 << 16);
          }
        }
      }
      __syncthreads();
      if (J.taps == 25) {
        for (int kk = 0; kk < kls; ++kk) {
          int slot = kk * 2 + lg;
          for (int dx = 0; dx < 5; ++dx) {
            int col = lcol + dx;
            const unsigned char* bbase =
                ldsb + (size_t)(wr * 4) * 2304 + slot * 576 + col * 16;
            // A hi: 10 frags (5 dy x 2 co)
            bf16x8 ah[5][2];
#pragma unroll
            for (int dy = 0; dy < 5; ++dy) {
              const unsigned short* wp =
                  W + (((size_t)(dy * 5 + dx) * KS + st * 2 + kk) * 4 + wc * 2) * 512 +
                  (size_t)l * 8;
              ah[dy][0] = *(const bf16x8*)wp;
              ah[dy][1] = *(const bf16x8*)(wp + 512);
            }
            // B hi: 8 row-frags
            bf16x8 bb[8];
#pragma unroll
            for (int j = 0; j < 8; ++j)
              bb[j] = *(const bf16x8*)(bbase + j * 2304);
            // al ping-pong (streamed per dy)
            bf16x8 al[2][2];
            {
              const unsigned short* wp =
                  W + AH + (((size_t)dx * KS + st * 2 + kk) * 4 + wc * 2) * 512 +
                  (size_t)l * 8;
              al[0][0] = *(const bf16x8*)wp;
              al[0][1] = *(const bf16x8*)(wp + 512);
            }
#pragma unroll
            for (int dy = 0; dy < 5; ++dy) {
              if (dy < 4) {
                const unsigned short* wp =
                    W + AH +
                    (((size_t)((dy + 1) * 5 + dx) * KS + st * 2 + kk) * 4 + wc * 2) *
                        512 +
                    (size_t)l * 8;
                al[(dy + 1) & 1][0] = *(const bf16x8*)wp;
                al[(dy + 1) & 1][1] = *(const bf16x8*)(wp + 512);
              }
#pragma unroll
              for (int j2 = 0; j2 < 4; ++j2) {
                acc[0][j2] = __builtin_amdgcn_mfma_f32_32x32x16_bf16(ah[dy][0], bb[j2 + dy], acc[0][j2], 0, 0, 0);
                acc[1][j2] = __builtin_amdgcn_mfma_f32_32x32x16_bf16(ah[dy][1], bb[j2 + dy], acc[1][j2], 0, 0, 0);
              }
#pragma unroll
              for (int j2 = 0; j2 < 4; ++j2) {
                acc[0][j2] = __builtin_amdgcn_mfma_f32_32x32x16_bf16(al[dy & 1][0], bb[j2 + dy], acc[0][j2], 0, 0, 0);
                acc[1][j2] = __builtin_amdgcn_mfma_f32_32x32x16_bf16(al[dy & 1][1], bb[j2 + dy], acc[1][j2], 0, 0, 0);
              }
            }
            // B lo: overwrite bb, hl pass (ah x bl)
#pragma unroll
            for (int j = 0; j < 8; ++j)
              bb[j] = *(const bf16x8*)(bbase + j * 2304 + 27648);
#pragma unroll
            for (int dy = 0; dy < 5; ++dy) {
#pragma unroll
              for (int j2 = 0; j2 < 4; ++j2) {
                acc[0][j2] = __builtin_amdgcn_mfma_f32_32x32x16_bf16(ah[dy][0], bb[j2 + dy], acc[0][j2], 0, 0, 0);
                acc[1][j2] = __builtin_amdgcn_mfma_f32_32x32x16_bf16(ah[dy][1], bb[j2 + dy], acc[1][j2], 0, 0, 0);
              }
            }
          }
        }
      } else {  // taps == 1 (center tap only)
        for (int kk = 0; kk < kls; ++kk) {
          int slot = kk * 2 + lg;
          const unsigned char* bbase =
              ldsb + (size_t)(wr * 4 + 2) * 2304 + slot * 576 + (lcol + 2) * 16;
          const unsigned short* wp =
              W + (((size_t)0 * KS + st * 2 + kk) * 4 + wc * 2) * 512 + (size_t)l * 8;
          bf16x8 ah0 = *(const bf16x8*)wp;
          bf16x8 ah1 = *(const bf16x8*)(wp + 512);
          bf16x8 al0 = *(const bf16x8*)(wp + AH);
          bf16x8 al1 = *(const bf16x8*)(wp + AH + 512);
          bf16x8 bb[4];
#pragma unroll
          for (int j2 = 0; j2 < 4; ++j2)
            bb[j2] = *(const bf16x8*)(bbase + j2 * 2304);
#pragma unroll
          for (int j2 = 0; j2 < 4; ++j2) {
            acc[0][j2] = __builtin_amdgcn_mfma_f32_32x32x16_bf16(ah0, bb[j2], acc[0][j2], 0, 0, 0);
            acc[1][j2] = __builtin_amdgcn_mfma_f32_32x32x16_bf16(ah1, bb[j2], acc[1][j2], 0, 0, 0);
            acc[0][j2] = __builtin_amdgcn_mfma_f32_32x32x16_bf16(al0, bb[j2], acc[0][j2], 0, 0, 0);
            acc[1][j2] = __builtin_amdgcn_mfma_f32_32x32x16_bf16(al1, bb[j2], acc[1][j2], 0, 0, 0);
          }
#pragma unroll
          for (int j2 = 0; j2 < 4; ++j2)
            bb[j2] = *(const bf16x8*)(bbase + j2 * 2304 + 27648);
#pragma unroll
          for (int j2 = 0; j2 < 4; ++j2) {
            acc[0][j2] = __builtin_amdgcn_mfma_f32_32x32x16_bf16(ah0, bb[j2], acc[0][j2], 0, 0, 0);
            acc[1][j2] = __builtin_amdgcn_mfma_f32_32x32x16_bf16(ah1, bb[j2], acc[1][j2], 0, 0, 0);
          }
        }
      }
    }
  }
  // store: D col = lane&31 (px), row = (reg&3) + 8*(reg>>2) + 4*(lane>>5)
#pragma unroll
  for (int r = 0; r < 2; ++r) {
#pragma unroll
    for (int j2 = 0; j2 < 4; ++j2) {
      int prow = r0 + wr * 4 + j2;
      float* op = J.out + (((size_t)b * J.outCo) << 10) + prow * 32 + lcol;
#pragma unroll
      for (int q = 0; q < 16; ++q) {
        int coLoc = wc * 64 + r * 32 + 4 * lg + (q & 3) + 8 * (q >> 2);
        if (coLoc < J.coCnt)
          op[(size_t)(J.coBase + coLoc) << 10] = acc[r][j2][q];
      }
    }
  }
}

// ---------------------------------------------------------------------------
__global__ void build_net_k(const float* __restrict__ frames0, float* __restrict__ net,
                            int t) {
  int idx = blockIdx.x * 256 + threadIdx.x;
  int b = idx >> 14, ch = (idx >> 10) & 15, p = idx & 1023;
  int y = p >> 5, x = p & 31, py = ch >> 2, px = ch & 3;
  net[idx] = frames0[((size_t)b * 10 + t) * 16384 + (y * 4 + py) * 128 + (x * 4 + px)];
}

// STH [b][256]: i,f,g,o ; STM [b][192]: i',f',g'
__global__ void st_gate1_k(const float* __restrict__ sth, const float* __restrict__ stm,
                           float* __restrict__ c, float* __restrict__ m) {
  int idx = blockIdx.x * 256 + threadIdx.x;
  int b = idx >> 16, r = idx & 65535;
  const float* hb = sth + (size_t)b * 262144 + r;
  const float* mb = stm + (size_t)b * 196608 + r;
  float cn = sigf(hb[65536] + 1.f) * c[idx] + sigf(hb[0]) * tanhf(hb[131072]);
  float mn = sigf(mb[65536] + 1.f) * m[idx] + sigf(mb[0]) * tanhf(mb[131072]);
  c[idx] = cn;
  m[idx] = mn;
}

__global__ void st_gate2_k(const float* __restrict__ sth, const float* __restrict__ oS,
                           const float* __restrict__ cl, float* __restrict__ h,
                           float* __restrict__ diff) {
  int idx = blockIdx.x * 256 + threadIdx.x;
  int b = idx >> 16, r = idx & 65535;
  float o = sigf(sth[(size_t)b * 262144 + 196608 + r] + oS[idx]);
  float hn = o * tanhf(cl[idx]);
  float old = h[idx];
  h[idx] = hn;
  diff[idx] = hn - old;
}

// merged MN conv output: chunks i,g,f,o
__global__ void mimn_gate_k(const float* __restrict__ MN, float* __restrict__ dh,
                            float* __restrict__ dc, const float* __restrict__ ctw,
                            const float* __restrict__ ocw) {
  int idx = blockIdx.x * 256 + threadIdx.x;
  int b = idx >> 16, r = idx & 65535;
  const float* q = MN + (size_t)b * 262144 + r;
  float c0 = dc[idx];
  float cn = sigf(q[131072] + c0 * ctw[65536 + r] + 1.f) * c0 +
             sigf(q[0] + c0 * ctw[r]) * tanhf(q[65536]);
  float hn = sigf(q[196608] + cn * ocw[r]) * tanhf(cn);
  dc[idx] = cn;
  dh[idx] = hn;
}

// S:i,g,f,o  T:i,g,o  X:i,g,f,o  QH/QX:i,g,f,o (summed)
__global__ void mb_gate1_k(const float* __restrict__ Sb, const float* __restrict__ Tb,
                           const float* __restrict__ Xb, const float* __restrict__ QH,
                           const float* __restrict__ QX, float* __restrict__ m,
                           float* __restrict__ c, float* __restrict__ cc,
                           const float* __restrict__ ctw, const float* __restrict__ ocw) {
  int idx = blockIdx.x * 256 + threadIdx.x;
  int b = idx >> 16, r = idx & 65535;
  const float* sb = Sb + (size_t)b * 262144 + r;
  const float* tb = Tb + (size_t)b * 196608 + r;
  const float* xb = Xb + (size_t)b * 262144 + r;
  const float* qh = QH + (size_t)b * 262144 + r;
  const float* qx = QX + (size_t)b * 262144 + r;
  float i_s = sb[0], g_s = sb[65536], f_s = sb[131072];
  float i_t = tb[0], g_t = tb[65536];
  float i_x = xb[0], g_x = xb[65536], f_x = xb[131072];
  float m0 = m[idx];
  float nm = sigf(f_x + f_s + 1.f) * m0 + sigf(i_x + i_s) * tanhf(g_x + g_s);
  float q_i = qh[0] + qx[0], q_g = qh[65536] + qx[65536];
  float q_f = qh[131072] + qx[131072], q_o = qh[196608] + qx[196608];
  float cc0 = cc[idx];
  float mims = sigf(q_f + cc0 * ctw[65536 + r] + 1.f) * cc0 +
               sigf(q_i + cc0 * ctw[r]) * tanhf(q_g);
  float h2 = sigf(q_o + mims * ocw[r]) * tanhf(mims);
  float nc = h2 + sigf(i_x + i_t) * tanhf(g_x + g_t);
  m[idx] = nm;
  c[idx] = nc;
  cc[idx] = mims;
}

// fused conv1(mb_last over [cI,m0]) + 3-term output gate. grid 128
__global__ __launch_bounds__(256) void mb_gate2c1_k(
    const float* __restrict__ cI, const float* __restrict__ m0,
    const float* __restrict__ wl, const float* __restrict__ Sb,
    const float* __restrict__ Tb, const float* __restrict__ Xb,
    float* __restrict__ h) {
  int blk = blockIdx.x;
  int coB = blk & 3, pb = (blk >> 2) & 3, b = blk >> 4;
  int tid = threadIdx.x, px = pb * 256 + tid;
  float acc[16];
#pragma unroll
  for (int c = 0; c < 16; ++c) acc[c] = 0.f;
  const float* ib1 = cI + (size_t)b * 65536 + px;
  const float* ib2 = m0 + (size_t)b * 65536 + px;
  for (int ci = 0; ci < 64; ++ci) {
    float v1 = ib1[ci * 1024], v2 = ib2[ci * 1024];
    const float* w1 = wl + (size_t)ci * 64 + coB * 16;
    const float* w2 = wl + (size_t)(64 + ci) * 64 + coB * 16;
#pragma unroll
    for (int c = 0; c < 16; ++c) {
      acc[c] = fmaf(w1[c], v1, acc[c]);
      acc[c] = fmaf(w2[c], v2, acc[c]);
    }
  }
#pragma unroll
  for (int c = 0; c < 16; ++c) {
    int co = coB * 16 + c;
    size_t o = (size_t)co * 1024 + px;
    float osum = Xb[(size_t)b * 262144 + 196608 + o] +
                 Tb[(size_t)b * 196608 + 131072 + o] +
                 Sb[(size_t)b * 262144 + 196608 + o];
    h[(size_t)b * 65536 + o] = sigf(osum) * tanhf(acc[c]);
  }
}

// final conv1 w_last + unpatchify. grid 32
__global__ __launch_bounds__(256) void xgen_k(const float* __restrict__ h3,
                                              const float* __restrict__ wwl,
                                              float* __restrict__ xg,
                                              float* __restrict__ out, int t) {
  int blk = blockIdx.x;
  int pb = blk & 3, b = blk >> 2;
  int tid = threadIdx.x, px = pb * 256 + tid;
  float acc[16];
#pragma unroll
  for (int c = 0; c < 16; ++c) acc[c] = 0.f;
  const float* ib = h3 + (size_t)b * 65536 + px;
  for (int ci = 0; ci < 64; ++ci) {
    float v = ib[ci * 1024];
    const float* w = wwl + (size_t)ci * 16;
#pragma unroll
    for (int c = 0; c < 16; ++c) acc[c] = fmaf(w[c], v, acc[c]);
  }
  int y = px >> 5, x = px & 31;
#pragma unroll
  for (int c = 0; c < 16; ++c) {
    xg[(size_t)b * 16384 + (size_t)c * 1024 + px] = acc[c];
    if (t >= 9) {
      int py = c >> 2, pxs = c & 3;
      out[((size_t)b * 10 + (t - 9)) * 16384 + (y * 4 + py) * 128 + (x * 4 + pxs)] =
          acc[c];
    }
  }
}

// ---------------------------------------------------------------------------
extern "C" void kernel_launch(void* const* d_in, const int* in_sizes, int n_in,
                              void* d_out, int out_size, void* d_ws, size_t ws_size,
                              hipStream_t stream) {
  const float* frames0 = (const float*)d_in[0];
  const float* st_cx = (const float*)d_in[2];
  const float* st_ch = (const float*)d_in[3];
  const float* st_cm = (const float*)d_in[4];
  const float* st_co = (const float*)d_in[5];
  const float* st_cl = (const float*)d_in[6];
  const float* mb_t = (const float*)d_in[7];
  const float* mb_s = (const float*)d_in[8];
  const float* mb_x = (const float*)d_in[9];
  const float* mb_mh = (const float*)d_in[10];
  const float* mb_mx = (const float*)d_in[11];
  const float* mb_ctw = (const float*)d_in[12];
  const float* mb_ocw = (const float*)d_in[13];
  const float* mb_last = (const float*)d_in[14];
  const float* mn_ch = (const float*)d_in[15];
  const float* mn_cx = (const float*)d_in[16];
  const float* mn_ctw = (const float*)d_in[17];
  const float* mn_ocw = (const float*)d_in[18];
  const float* w_last = (const float*)d_in[19];
  float* out = (float*)d_out;

  float* ws = (float*)d_ws;
  size_t off = 0;
  auto A_ = [&](size_t n) { float* p = ws + off; off += n; return p; };
  float* hs[4]; for (int i = 0; i < 4; ++i) hs[i] = A_(S);
  float* cs[4]; for (int i = 0; i < 4; ++i) cs[i] = A_(S);
  float* memb = A_(S);
  float* dh[3]; for (int i = 0; i < 3; ++i) dh[i] = A_(S);
  float* dcb[3]; for (int i = 0; i < 3; ++i) dcb[i] = A_(S);
  float* ccb[3]; for (int i = 0; i < 3; ++i) ccb[i] = A_(S);
  float* diffb = A_(S);
  size_t zeroFloats = off;  // 19*S
  float* xgen = A_(131072);
  float* netb = A_(131072);
  float* R1 = A_(4 * S);   // STH / MN / QX
  float* R2 = A_(3 * S);   // STM / T
  float* R3 = A_(4 * S);   // X
  float* R5 = A_(4 * S);   // S
  float* RM = A_(4 * S);   // MH (QH)
  float* B64a = A_(S);     // STO
  float* B64b = A_(S);     // CL
  float* wtmbl[3]; for (int li = 0; li < 3; ++li) wtmbl[li] = A_(8192);
  float* wtwl = A_(1024);
  unsigned short* warena = (unsigned short*)(ws + off);

  size_t wOff = 0;
  auto alloc = [&](int taps, int KS) {
    size_t o = wOff;
    wOff += (size_t)2 * taps * KS * 2048;
    return o;
  };
  size_t oSTH0n = alloc(25, 1), oSTH0h = alloc(25, 4);
  size_t oSTH1n = alloc(25, 1), oSTH1h = alloc(25, 4);
  size_t oSTM0n = alloc(25, 1), oSTM0m = alloc(25, 4);
  size_t oSTM1n = alloc(25, 1), oSTM1m = alloc(25, 4);
  size_t oSTOa = alloc(25, 4), oSTOb = alloc(25, 4);
  size_t oCLa = alloc(1, 4), oCLb = alloc(1, 4);
  size_t oMNa0[3], oMNa1[3], oMNb0[3], oMNb1[3], oS0[3], oS1[3], oT0[3], oT1[3],
      oX0[3], oX1[3], oMH0[3], oMH1[3], oMX0[3], oMX1[3];
  for (int li = 0; li < 3; ++li) {
    oMNa0[li] = alloc(25, 4); oMNa1[li] = alloc(25, 4);
    oMNb0[li] = alloc(25, 4); oMNb1[li] = alloc(25, 4);
    oS0[li] = alloc(25, 4); oS1[li] = alloc(25, 4);
    oT0[li] = alloc(25, 4); oT1[li] = alloc(25, 4);
    oX0[li] = alloc(25, 4); oX1[li] = alloc(25, 4);
    oMH0[li] = alloc(25, 4); oMH1[li] = alloc(25, 4);
    oMX0[li] = alloc(25, 4); oMX1[li] = alloc(25, 4);
  }
  if (ws_size < off * sizeof(float) + wOff * sizeof(unsigned short)) return;

  hipMemsetAsync(ws, 0, zeroFloats * sizeof(float), stream);
  hipMemsetAsync(warena, 0, wOff * sizeof(unsigned short), stream);

  auto packL = [&](size_t dstOff, const float* src, int srcRow0, int nRows,
                   int dstRow0, int ciBase, int cinSrc, int taps, int KS) {
    int total = taps * KS * 4 * 64;
    pack_k<<<(total + 255) / 256, 256, 0, stream>>>(warena + dstOff, src, srcRow0,
                                                    nRows, dstRow0, ciBase, cinSrc,
                                                    taps, KS);
  };
  // st_cx rows: i(0) f(64) g(128) i'(192) f'(256) g'(320) o(384)
  packL(oSTH0n, st_cx, 0, 128, 0, 0, 16, 25, 1);
  packL(oSTH0h, st_ch, 0, 128, 0, 0, 64, 25, 4);
  packL(oSTH1n, st_cx, 128, 64, 0, 0, 16, 25, 1);
  packL(oSTH1n, st_cx, 384, 64, 64, 0, 16, 25, 1);
  packL(oSTH1h, st_ch, 128, 128, 0, 0, 64, 25, 4);
  packL(oSTM0n, st_cx, 192, 128, 0, 0, 16, 25, 1);
  packL(oSTM0m, st_cm, 0, 128, 0, 0, 64, 25, 4);
  packL(oSTM1n, st_cx, 320, 64, 0, 0, 16, 25, 1);
  packL(oSTM1m, st_cm, 128, 64, 0, 0, 64, 25, 4);
  packL(oSTOa, st_co, 0, 64, 0, 0, 128, 25, 4);
  packL(oSTOb, st_co, 0, 64, 0, 64, 128, 25, 4);
  packL(oCLa, st_cl, 0, 64, 0, 0, 128, 1, 4);
  packL(oCLb, st_cl, 0, 64, 0, 64, 128, 1, 4);
  for (int li = 0; li < 3; ++li) {
    const float* ch = mn_ch + (size_t)li * 409600;
    const float* cx = mn_cx + (size_t)li * 409600;
    const float* mbs = mb_s + (size_t)li * 409600;
    const float* mbt = mb_t + (size_t)li * 307200;
    const float* mbx = mb_x + (size_t)li * 409600;
    const float* mmh = mb_mh + (size_t)li * 409600;
    const float* mmx = mb_mx + (size_t)li * 409600;
    packL(oMNa0[li], ch, 0, 128, 0, 0, 64, 25, 4);
    packL(oMNa1[li], ch, 128, 128, 0, 0, 64, 25, 4);
    packL(oMNb0[li], cx, 0, 128, 0, 0, 64, 25, 4);
    packL(oMNb1[li], cx, 128, 128, 0, 0, 64, 25, 4);
    packL(oS0[li], mbs, 0, 128, 0, 0, 64, 25, 4);
    packL(oS1[li], mbs, 128, 128, 0, 0, 64, 25, 4);
    packL(oT0[li], mbt, 0, 128, 0, 0, 64, 25, 4);
    packL(oT1[li], mbt, 128, 64, 0, 0, 64, 25, 4);
    packL(oX0[li], mbx, 0, 128, 0, 0, 64, 25, 4);
    packL(oX1[li], mbx, 128, 128, 0, 0, 64, 25, 4);
    packL(oMH0[li], mmh, 0, 128, 0, 0, 64, 25, 4);
    packL(oMH1[li], mmh, 128, 128, 0, 0, 64, 25, 4);
    packL(oMX0[li], mmx, 0, 128, 0, 0, 64, 25, 4);
    packL(oMX1[li], mmx, 128, 128, 0, 0, 64, 25, 4);
    tr1_k<<<32, 256, 0, stream>>>(mb_last + (size_t)li * 8192, wtmbl[li], 128, 64);
  }
  tr1_k<<<4, 256, 0, stream>>>(w_last, wtwl, 64, 16);

  auto mkj = [&](const float* x0, size_t w0, int cin0, const float* x1, size_t w1,
                 int cin1, int taps, float* o, int outCo, int coBase, int coCnt) {
    Job j;
    j.x0 = x0; j.w0 = warena + w0; j.cin0 = cin0;
    j.x1 = x1; j.w1 = warena + w1; j.cin1 = cin1;
    j.taps = taps; j.out = o; j.outCo = outCo; j.coBase = coBase; j.coCnt = coCnt;
    j.blockStart = 0;
    return j;
  };
  auto launchB = [&](Batch& bt) {
    int nb = 0;
    for (int q = 0; q < bt.n; ++q) { bt.j[q].blockStart = nb; nb += 32; }
    convmf4_k<<<nb, 256, 0, stream>>>(bt);
  };

  for (int t = 0; t < 19; ++t) {
    const float* stIn = (t < 10) ? netb : xgen;
    if (t < 10) build_net_k<<<512, 256, 0, stream>>>(frames0, netb, t);
    {
      Batch P; P.n = 4;
      P.j[0] = mkj(stIn, oSTH0n, 16, hs[0], oSTH0h, 64, 25, R1, 256, 0, 128);
      P.j[1] = mkj(stIn, oSTH1n, 16, hs[0], oSTH1h, 64, 25, R1, 256, 128, 128);
      P.j[2] = mkj(stIn, oSTM0n, 16, memb, oSTM0m, 64, 25, R2, 192, 0, 128);
      P.j[3] = mkj(stIn, oSTM1n, 16, memb, oSTM1m, 64, 25, R2, 192, 128, 64);
      launchB(P);
    }
    st_gate1_k<<<2048, 256, 0, stream>>>(R1, R2, cs[0], memb);
    {
      Batch P; P.n = 2;
      P.j[0] = mkj(cs[0], oSTOa, 64, memb, oSTOb, 64, 25, B64a, 64, 0, 64);
      P.j[1] = mkj(cs[0], oCLa, 64, memb, oCLb, 64, 1, B64b, 64, 0, 64);
      launchB(P);
    }
    st_gate2_k<<<2048, 256, 0, stream>>>(R1, B64a, B64b, hs[0], diffb);

    for (int i = 1; i < 4; ++i) {
      int li = i - 1;
      const float* din = (i == 1) ? diffb : dh[i - 2];
      {
        Batch P; int n = 0;
        if (t >= 1) {
          P.j[n++] = mkj(dh[li], oMNa0[li], 64, din, oMNb0[li], 64, 25, R1, 256, 0, 128);
          P.j[n++] = mkj(dh[li], oMNa1[li], 64, din, oMNb1[li], 64, 25, R1, 256, 128, 128);
        }
        P.j[n++] = mkj(memb, oS0[li], 64, nullptr, oS0[li], 0, 25, R5, 256, 0, 128);
        P.j[n++] = mkj(memb, oS1[li], 64, nullptr, oS1[li], 0, 25, R5, 256, 128, 128);
        P.j[n++] = mkj(hs[i - 1], oX0[li], 64, nullptr, oX0[li], 0, 25, R3, 256, 0, 128);
        P.j[n++] = mkj(hs[i - 1], oX1[li], 64, nullptr, oX1[li], 0, 25, R3, 256, 128, 128);
        P.j[n++] = mkj(hs[i], oT0[li], 64, nullptr, oT0[li], 0, 25, R2, 192, 0, 128);
        P.j[n++] = mkj(hs[i], oT1[li], 64, nullptr, oT1[li], 0, 25, R2, 192, 128, 64);
        P.j[n++] = mkj(cs[i], oMH0[li], 64, nullptr, oMH0[li], 0, 25, RM, 256, 0, 128);
        P.j[n++] = mkj(cs[i], oMH1[li], 64, nullptr, oMH1[li], 0, 25, RM, 256, 128, 128);
        P.n = n;
        launchB(P);
      }
      if (t >= 1)
        mimn_gate_k<<<2048, 256, 0, stream>>>(R1, dh[li], dcb[li],
                                              mn_ctw + (size_t)li * 131072,
                                              mn_ocw + (size_t)li * 65536);
      {
        Batch P; P.n = 2;
        P.j[0] = mkj(dh[li], oMX0[li], 64, nullptr, oMX0[li], 0, 25, R1, 256, 0, 128);
        P.j[1] = mkj(dh[li], oMX1[li], 64, nullptr, oMX1[li], 0, 25, R1, 256, 128, 128);
        launchB(P);
      }
      mb_gate1_k<<<2048, 256, 0, stream>>>(R5, R2, R3, RM, R1, memb, cs[i], ccb[li],
                                           mb_ctw + (size_t)li * 131072,
                                           mb_ocw + (size_t)li * 65536);
      mb_gate2c1_k<<<128, 256, 0, stream>>>(cs[i], memb, wtmbl[li], R5, R2, R3, hs[i]);
    }
    xgen_k<<<32, 256, 0, stream>>>(hs[3], wtwl, xgen, out, t);
  }
}

// Round 7
// 20672.836 us; speedup vs baseline: 1.1354x; 1.1354x over previous
//
#include <hip/hip_runtime.h>
#include <math.h>

// ---------------------------------------------------------------------------
// MIM RNN round 6: slot-major conflict-free LDS + dy-rolling inner loop
// (120 MFMA / 16 B-reads) + per-dy A ping-pong prefetch. Split-bf16 (3 pass).
// ---------------------------------------------------------------------------

#define S 524288  // 8*64*1024

typedef __attribute__((ext_vector_type(8))) short bf16x8;
typedef __attribute__((ext_vector_type(16))) float f32x16;

__device__ __forceinline__ float sigf(float x) { return 1.0f / (1.0f + expf(-x)); }
__device__ __forceinline__ unsigned short f2bf(float f) {
  unsigned u = __float_as_uint(f);
  u += 0x7fffu + ((u >> 16) & 1u);
  return (unsigned short)(u >> 16);
}
__device__ __forceinline__ float bf2f(unsigned short h) {
  return __uint_as_float(((unsigned)h) << 16);
}

struct Job {
  const float* x0; const unsigned short* w0; int cin0;
  const float* x1; const unsigned short* w1; int cin1;
  int taps; float* out; int outCo; int coBase; int coCnt; int blockStart;
};
struct Batch { Job j[10]; int n; };

// ---------------------------------------------------------------------------
// Weight prepack: W'[half][tap][ks][coB4][lane64][8] bf16.
__global__ void pack_k(unsigned short* dst, const float* src, int srcRow0,
                       int nRows, int dstRow0, int ciBase, int cinSrc, int taps,
                       int KS) {
  int idx = blockIdx.x * 256 + threadIdx.x;
  int total = taps * KS * 4 * 64;
  if (idx >= total) return;
  int l = idx & 63;
  int cb = (idx >> 6) & 3;
  int rest = idx >> 8;
  int ks = rest % KS, tap = rest / KS;
  int co_d = cb * 32 + (l & 31);
  if (co_d < dstRow0 || co_d >= dstRow0 + nRows) return;
  int srcRow = srcRow0 + (co_d - dstRow0);
  size_t AH = (size_t)taps * KS * 2048;
  size_t base = ((size_t)(tap * KS + ks) * 4 + cb) * 512 + (size_t)l * 8;
#pragma unroll
  for (int j = 0; j < 8; ++j) {
    int ci = ciBase + ks * 16 + (l >> 5) * 8 + j;
    float v = src[((size_t)srcRow * cinSrc + ci) * taps + tap];
    unsigned short hi = f2bf(v);
    unsigned short lo = f2bf(v - bf2f(hi));
    dst[base + j] = hi;
    dst[AH + base + j] = lo;
  }
}

__global__ void tr1_k(const float* __restrict__ src, float* __restrict__ dst,
                      int Cin, int Cout) {
  int idx = blockIdx.x * 256 + threadIdx.x;
  if (idx >= Cout * Cin) return;
  int ci = idx % Cin, co = idx / Cin;
  dst[(size_t)ci * Cout + co] = src[idx];
}

// ---------------------------------------------------------------------------
// Conv: block = 128co x 256px (8 img rows), 4 waves = 2 wc x 2 wr.
// LDS: [half][12 rows][4 slots][36 cols x 16B]; row stride 2304B, slot 576B.
// A wave's b128 read = contiguous 512B per 32-lane group -> conflict-free.
// Inner: per (kk,dx) roll BH/BL over 8 rows, 5 dy x 24 MFMA; A ping-pong/dy.
__global__ __launch_bounds__(256, 2) void convmf5_k(Batch bt) {
  int blk = blockIdx.x;
  int ji = 0;
#pragma unroll
  for (int q = 1; q < 10; ++q)
    if (q < bt.n && blk >= bt.j[q].blockStart) ji = q;
  Job J = bt.j[ji];
  int local = blk - J.blockStart;
  int pxg = local & 3;
  int b = local >> 2;
  int r0 = pxg * 8;
  int tid = threadIdx.x, l = tid & 63, wv = tid >> 6;
  int wc = wv & 1, wr = wv >> 1;
  int lcol = l & 31, lg = l >> 5;

  __shared__ __align__(16) unsigned char lds[2][12][2304];
  unsigned char* ldsb = &lds[0][0][0];

  f32x16 acc[2][4];
#pragma unroll
  for (int r = 0; r < 2; ++r)
#pragma unroll
    for (int j2 = 0; j2 < 4; ++j2)
#pragma unroll
      for (int q = 0; q < 16; ++q) acc[r][j2][q] = 0.f;

  {  // zero halo cols 0,1,34,35 once (disjoint from staged cols 2..33)
    int e = tid;
#pragma unroll
    for (int it = 0; it < 2; ++it, e += 256)
      if (e < 384) {
        int hh = e & 1, sl = (e >> 1) & 3;
        int rq = e >> 3;  // 0..47
        int row = rq % 12, cq = rq / 12;
        int col = cq < 2 ? cq : 32 + cq;
        float4 z = {0.f, 0.f, 0.f, 0.f};
        *(float4*)(ldsb + hh * 27648 + row * 2304 + sl * 576 + col * 16) = z;
      }
  }

  for (int s = 0; s < 2; ++s) {
    const float* X = s ? J.x1 : J.x0;
    const unsigned short* W = s ? J.w1 : J.w0;
    int cin = s ? J.cin1 : J.cin0;
    if (cin == 0) continue;
    int KS = cin >> 4;
    size_t AH = (size_t)J.taps * KS * 2048;
    int nst = (cin + 31) >> 5;
    for (int st = 0; st < nst; ++st) {
      int ciCnt = cin - st * 32;
      if (ciCnt > 32) ciCnt = 32;
      int kls = ciCnt >> 4;  // 1 or 2
      auto aoff = [&](int tap, int kk2) {
        return (((size_t)tap * KS + st * 2 + kk2) * 4 + wc * 2) * 512 +
               (size_t)l * 8;
      };
      // A prologue for (dy0,kk0,dx0): issued BEFORE barriers -> flies under
      // the LDS staging.
      bf16x8 cah0, cah1, cal0, cal1, nah0, nah1, nal0, nal1;
      {
        const unsigned short* wp = W + aoff(0, 0);
        cah0 = *(const bf16x8*)wp;
        cah1 = *(const bf16x8*)(wp + 512);
        cal0 = *(const bf16x8*)(wp + AH);
        cal1 = *(const bf16x8*)(wp + AH + 512);
      }
      __syncthreads();
      // stage 12 rows (r0-2 .. r0+9) of up-to-32 ci, hi+lo halves
      for (int u = tid; u < 1536; u += 256) {
        int cp = u & 15;
        int xq = (u >> 4) & 7;
        int row = u >> 7;  // 0..11
        if (2 * cp < ciCnt) {
          int gy = r0 - 2 + row;
          float4 v0 = {0.f, 0.f, 0.f, 0.f}, v1 = {0.f, 0.f, 0.f, 0.f};
          if ((unsigned)gy < 32u) {
            const float* p0 =
                X + (((size_t)b * cin + st * 32 + 2 * cp) << 10) + gy * 32 + xq * 4;
            v0 = *(const float4*)p0;
            v1 = *(const float4*)(p0 + 1024);
          }
          const float* e0 = (const float*)&v0;
          const float* e1 = (const float*)&v1;
          int base0 = row * 2304 + (cp >> 2) * 576 + (cp & 3) * 4;
#pragma unroll
          for (int e = 0; e < 4; ++e) {
            int off2 = base0 + (xq * 4 + 2 + e) * 16;
            unsigned short h0 = f2bf(e0[e]);
            unsigned short h1 = f2bf(e1[e]);
            unsigned short lo0 = f2bf(e0[e] - bf2f(h0));
            unsigned short lo1 = f2bf(e1[e] - bf2f(h1));
            *(unsigned*)(ldsb + off2) = (unsigned)h0 | ((unsigned)h1 << 16);
            *(unsigned*)(ldsb + 27648 + off2) = (unsigned)lo0 | ((unsigned)lo1 << 16);
          }
        }
      }
      __syncthreads();
      if (J.taps == 25) {
        for (int kk = 0; kk < kls; ++kk) {
          int slot = kk * 2 + lg;
          for (int dx = 0; dx < 5; ++dx) {
            const unsigned char* bcol =
                ldsb + (size_t)slot * 576 + (lcol + dx) * 16;
            bf16x8 BH[8], BL[8];
#pragma unroll
            for (int j = 0; j < 4; ++j) {
              BH[j] = *(const bf16x8*)(bcol + (wr * 4 + j) * 2304);
              BL[j] = *(const bf16x8*)(bcol + (wr * 4 + j) * 2304 + 27648);
            }
            int nkk = (dx < 4) ? kk : kk + 1;
            int ndx = (dx < 4) ? dx + 1 : 0;
            bool lastIt = (kk == kls - 1) && (dx == 4);
#pragma unroll
            for (int dy = 0; dy < 5; ++dy) {
              if (dy < 4) {
                // roll B window + prefetch next dy's A
                BH[dy + 4] = *(const bf16x8*)(bcol + (wr * 4 + dy + 4) * 2304);
                BL[dy + 4] =
                    *(const bf16x8*)(bcol + (wr * 4 + dy + 4) * 2304 + 27648);
                const unsigned short* wp = W + aoff((dy + 1) * 5 + dx, kk);
                nah0 = *(const bf16x8*)wp;
                nah1 = *(const bf16x8*)(wp + 512);
                nal0 = *(const bf16x8*)(wp + AH);
                nal1 = *(const bf16x8*)(wp + AH + 512);
              } else if (!lastIt) {
                // cross-(kk,dx) prefetch of its dy0
                const unsigned short* wp = W + aoff(ndx, nkk);
                nah0 = *(const bf16x8*)wp;
                nah1 = *(const bf16x8*)(wp + 512);
                nal0 = *(const bf16x8*)(wp + AH);
                nal1 = *(const bf16x8*)(wp + AH + 512);
              }
              // 24 MFMAs: hh, lh, hl
#pragma unroll
              for (int j2 = 0; j2 < 4; ++j2) {
                acc[0][j2] = __builtin_amdgcn_mfma_f32_32x32x16_bf16(cah0, BH[dy + j2], acc[0][j2], 0, 0, 0);
                acc[1][j2] = __builtin_amdgcn_mfma_f32_32x32x16_bf16(cah1, BH[dy + j2], acc[1][j2], 0, 0, 0);
              }
#pragma unroll
              for (int j2 = 0; j2 < 4; ++j2) {
                acc[0][j2] = __builtin_amdgcn_mfma_f32_32x32x16_bf16(cal0, BH[dy + j2], acc[0][j2], 0, 0, 0);
                acc[1][j2] = __builtin_amdgcn_mfma_f32_32x32x16_bf16(cal1, BH[dy + j2], acc[1][j2], 0, 0, 0);
              }
#pragma unroll
              for (int j2 = 0; j2 < 4; ++j2) {
                acc[0][j2] = __builtin_amdgcn_mfma_f32_32x32x16_bf16(cah0, BL[dy + j2], acc[0][j2], 0, 0, 0);
                acc[1][j2] = __builtin_amdgcn_mfma_f32_32x32x16_bf16(cah1, BL[dy + j2], acc[1][j2], 0, 0, 0);
              }
              cah0 = nah0; cah1 = nah1; cal0 = nal0; cal1 = nal1;
            }
          }
        }
      } else {  // taps == 1 (center tap)
        for (int kk = 0; kk < kls; ++kk) {
          int slot = kk * 2 + lg;
          const unsigned char* bcol =
              ldsb + (size_t)slot * 576 + (lcol + 2) * 16;
          if (kk > 0) {
            const unsigned short* wp = W + aoff(0, kk);
            cah0 = *(const bf16x8*)wp;
            cah1 = *(const bf16x8*)(wp + 512);
            cal0 = *(const bf16x8*)(wp + AH);
            cal1 = *(const bf16x8*)(wp + AH + 512);
          }
          bf16x8 bb[4];
#pragma unroll
          for (int j2 = 0; j2 < 4; ++j2)
            bb[j2] = *(const bf16x8*)(bcol + (wr * 4 + j2 + 2) * 2304);
#pragma unroll
          for (int j2 = 0; j2 < 4; ++j2) {
            acc[0][j2] = __builtin_amdgcn_mfma_f32_32x32x16_bf16(cah0, bb[j2], acc[0][j2], 0, 0, 0);
            acc[1][j2] = __builtin_amdgcn_mfma_f32_32x32x16_bf16(cah1, bb[j2], acc[1][j2], 0, 0, 0);
            acc[0][j2] = __builtin_amdgcn_mfma_f32_32x32x16_bf16(cal0, bb[j2], acc[0][j2], 0, 0, 0);
            acc[1][j2] = __builtin_amdgcn_mfma_f32_32x32x16_bf16(cal1, bb[j2], acc[1][j2], 0, 0, 0);
          }
#pragma unroll
          for (int j2 = 0; j2 < 4; ++j2)
            bb[j2] = *(const bf16x8*)(bcol + (wr * 4 + j2 + 2) * 2304 + 27648);
#pragma unroll
          for (int j2 = 0; j2 < 4; ++j2) {
            acc[0][j2] = __builtin_amdgcn_mfma_f32_32x32x16_bf16(cah0, bb[j2], acc[0][j2], 0, 0, 0);
            acc[1][j2] = __builtin_amdgcn_mfma_f32_32x32x16_bf16(cah1, bb[j2], acc[1][j2], 0, 0, 0);
          }
        }
      }
    }
  }
  // store: D col = lane&31 (px), row = (reg&3) + 8*(reg>>2) + 4*(lane>>5)
#pragma unroll
  for (int r = 0; r < 2; ++r) {
#pragma unroll
    for (int j2 = 0; j2 < 4; ++j2) {
      int prow = r0 + wr * 4 + j2;
      float* op = J.out + (((size_t)b * J.outCo) << 10) + prow * 32 + lcol;
#pragma unroll
      for (int q = 0; q < 16; ++q) {
        int coLoc = wc * 64 + r * 32 + 4 * lg + (q & 3) + 8 * (q >> 2);
        if (coLoc < J.coCnt)
          op[(size_t)(J.coBase + coLoc) << 10] = acc[r][j2][q];
      }
    }
  }
}

// ---------------------------------------------------------------------------
__global__ void build_net_k(const float* __restrict__ frames0, float* __restrict__ net,
                            int t) {
  int idx = blockIdx.x * 256 + threadIdx.x;
  int b = idx >> 14, ch = (idx >> 10) & 15, p = idx & 1023;
  int y = p >> 5, x = p & 31, py = ch >> 2, px = ch & 3;
  net[idx] = frames0[((size_t)b * 10 + t) * 16384 + (y * 4 + py) * 128 + (x * 4 + px)];
}

// STH [b][256]: i,f,g,o ; STM [b][192]: i',f',g'
__global__ void st_gate1_k(const float* __restrict__ sth, const float* __restrict__ stm,
                           float* __restrict__ c, float* __restrict__ m) {
  int idx = blockIdx.x * 256 + threadIdx.x;
  int b = idx >> 16, r = idx & 65535;
  const float* hb = sth + (size_t)b * 262144 + r;
  const float* mb = stm + (size_t)b * 196608 + r;
  float cn = sigf(hb[65536] + 1.f) * c[idx] + sigf(hb[0]) * tanhf(hb[131072]);
  float mn = sigf(mb[65536] + 1.f) * m[idx] + sigf(mb[0]) * tanhf(mb[131072]);
  c[idx] = cn;
  m[idx] = mn;
}

__global__ void st_gate2_k(const float* __restrict__ sth, const float* __restrict__ oS,
                           const float* __restrict__ cl, float* __restrict__ h,
                           float* __restrict__ diff) {
  int idx = blockIdx.x * 256 + threadIdx.x;
  int b = idx >> 16, r = idx & 65535;
  float o = sigf(sth[(size_t)b * 262144 + 196608 + r] + oS[idx]);
  float hn = o * tanhf(cl[idx]);
  float old = h[idx];
  h[idx] = hn;
  diff[idx] = hn - old;
}

// merged MN conv output: chunks i,g,f,o
__global__ void mimn_gate_k(const float* __restrict__ MN, float* __restrict__ dh,
                            float* __restrict__ dc, const float* __restrict__ ctw,
                            const float* __restrict__ ocw) {
  int idx = blockIdx.x * 256 + threadIdx.x;
  int b = idx >> 16, r = idx & 65535;
  const float* q = MN + (size_t)b * 262144 + r;
  float c0 = dc[idx];
  float cn = sigf(q[131072] + c0 * ctw[65536 + r] + 1.f) * c0 +
             sigf(q[0] + c0 * ctw[r]) * tanhf(q[65536]);
  float hn = sigf(q[196608] + cn * ocw[r]) * tanhf(cn);
  dc[idx] = cn;
  dh[idx] = hn;
}

// S:i,g,f,o  T:i,g,o  X:i,g,f,o  QH/QX:i,g,f,o (summed)
__global__ void mb_gate1_k(const float* __restrict__ Sb, const float* __restrict__ Tb,
                           const float* __restrict__ Xb, const float* __restrict__ QH,
                           const float* __restrict__ QX, float* __restrict__ m,
                           float* __restrict__ c, float* __restrict__ cc,
                           const float* __restrict__ ctw, const float* __restrict__ ocw) {
  int idx = blockIdx.x * 256 + threadIdx.x;
  int b = idx >> 16, r = idx & 65535;
  const float* sb = Sb + (size_t)b * 262144 + r;
  const float* tb = Tb + (size_t)b * 196608 + r;
  const float* xb = Xb + (size_t)b * 262144 + r;
  const float* qh = QH + (size_t)b * 262144 + r;
  const float* qx = QX + (size_t)b * 262144 + r;
  float i_s = sb[0], g_s = sb[65536], f_s = sb[131072];
  float i_t = tb[0], g_t = tb[65536];
  float i_x = xb[0], g_x = xb[65536], f_x = xb[131072];
  float m0 = m[idx];
  float nm = sigf(f_x + f_s + 1.f) * m0 + sigf(i_x + i_s) * tanhf(g_x + g_s);
  float q_i = qh[0] + qx[0], q_g = qh[65536] + qx[65536];
  float q_f = qh[131072] + qx[131072], q_o = qh[196608] + qx[196608];
  float cc0 = cc[idx];
  float mims = sigf(q_f + cc0 * ctw[65536 + r] + 1.f) * cc0 +
               sigf(q_i + cc0 * ctw[r]) * tanhf(q_g);
  float h2 = sigf(q_o + mims * ocw[r]) * tanhf(mims);
  float nc = h2 + sigf(i_x + i_t) * tanhf(g_x + g_t);
  m[idx] = nm;
  c[idx] = nc;
  cc[idx] = mims;
}

// fused conv1(mb_last over [cI,m0]) + 3-term output gate. grid 128
__global__ __launch_bounds__(256) void mb_gate2c1_k(
    const float* __restrict__ cI, const float* __restrict__ m0,
    const float* __restrict__ wl, const float* __restrict__ Sb,
    const float* __restrict__ Tb, const float* __restrict__ Xb,
    float* __restrict__ h) {
  int blk = blockIdx.x;
  int coB = blk & 3, pb = (blk >> 2) & 3, b = blk >> 4;
  int tid = threadIdx.x, px = pb * 256 + tid;
  float acc[16];
#pragma unroll
  for (int c = 0; c < 16; ++c) acc[c] = 0.f;
  const float* ib1 = cI + (size_t)b * 65536 + px;
  const float* ib2 = m0 + (size_t)b * 65536 + px;
  for (int ci = 0; ci < 64; ++ci) {
    float v1 = ib1[ci * 1024], v2 = ib2[ci * 1024];
    const float* w1 = wl + (size_t)ci * 64 + coB * 16;
    const float* w2 = wl + (size_t)(64 + ci) * 64 + coB * 16;
#pragma unroll
    for (int c = 0; c < 16; ++c) {
      acc[c] = fmaf(w1[c], v1, acc[c]);
      acc[c] = fmaf(w2[c], v2, acc[c]);
    }
  }
#pragma unroll
  for (int c = 0; c < 16; ++c) {
    int co = coB * 16 + c;
    size_t o = (size_t)co * 1024 + px;
    float osum = Xb[(size_t)b * 262144 + 196608 + o] +
                 Tb[(size_t)b * 196608 + 131072 + o] +
                 Sb[(size_t)b * 262144 + 196608 + o];
    h[(size_t)b * 65536 + o] = sigf(osum) * tanhf(acc[c]);
  }
}

// final conv1 w_last + unpatchify. grid 32
__global__ __launch_bounds__(256) void xgen_k(const float* __restrict__ h3,
                                              const float* __restrict__ wwl,
                                              float* __restrict__ xg,
                                              float* __restrict__ out, int t) {
  int blk = blockIdx.x;
  int pb = blk & 3, b = blk >> 2;
  int tid = threadIdx.x, px = pb * 256 + tid;
  float acc[16];
#pragma unroll
  for (int c = 0; c < 16; ++c) acc[c] = 0.f;
  const float* ib = h3 + (size_t)b * 65536 + px;
  for (int ci = 0; ci < 64; ++ci) {
    float v = ib[ci * 1024];
    const float* w = wwl + (size_t)ci * 16;
#pragma unroll
    for (int c = 0; c < 16; ++c) acc[c] = fmaf(w[c], v, acc[c]);
  }
  int y = px >> 5, x = px & 31;
#pragma unroll
  for (int c = 0; c < 16; ++c) {
    xg[(size_t)b * 16384 + (size_t)c * 1024 + px] = acc[c];
    if (t >= 9) {
      int py = c >> 2, pxs = c & 3;
      out[((size_t)b * 10 + (t - 9)) * 16384 + (y * 4 + py) * 128 + (x * 4 + pxs)] =
          acc[c];
    }
  }
}

// ---------------------------------------------------------------------------
extern "C" void kernel_launch(void* const* d_in, const int* in_sizes, int n_in,
                              void* d_out, int out_size, void* d_ws, size_t ws_size,
                              hipStream_t stream) {
  const float* frames0 = (const float*)d_in[0];
  const float* st_cx = (const float*)d_in[2];
  const float* st_ch = (const float*)d_in[3];
  const float* st_cm = (const float*)d_in[4];
  const float* st_co = (const float*)d_in[5];
  const float* st_cl = (const float*)d_in[6];
  const float* mb_t = (const float*)d_in[7];
  const float* mb_s = (const float*)d_in[8];
  const float* mb_x = (const float*)d_in[9];
  const float* mb_mh = (const float*)d_in[10];
  const float* mb_mx = (const float*)d_in[11];
  const float* mb_ctw = (const float*)d_in[12];
  const float* mb_ocw = (const float*)d_in[13];
  const float* mb_last = (const float*)d_in[14];
  const float* mn_ch = (const float*)d_in[15];
  const float* mn_cx = (const float*)d_in[16];
  const float* mn_ctw = (const float*)d_in[17];
  const float* mn_ocw = (const float*)d_in[18];
  const float* w_last = (const float*)d_in[19];
  float* out = (float*)d_out;

  float* ws = (float*)d_ws;
  size_t off = 0;
  auto A_ = [&](size_t n) { float* p = ws + off; off += n; return p; };
  float* hs[4]; for (int i = 0; i < 4; ++i) hs[i] = A_(S);
  float* cs[4]; for (int i = 0; i < 4; ++i) cs[i] = A_(S);
  float* memb = A_(S);
  float* dh[3]; for (int i = 0; i < 3; ++i) dh[i] = A_(S);
  float* dcb[3]; for (int i = 0; i < 3; ++i) dcb[i] = A_(S);
  float* ccb[3]; for (int i = 0; i < 3; ++i) ccb[i] = A_(S);
  float* diffb = A_(S);
  size_t zeroFloats = off;  // 19*S
  float* xgen = A_(131072);
  float* netb = A_(131072);
  float* R1 = A_(4 * S);   // STH / MN / QX
  float* R2 = A_(3 * S);   // STM / T
  float* R3 = A_(4 * S);   // X
  float* R5 = A_(4 * S);   // S
  float* RM = A_(4 * S);   // MH (QH)
  float* B64a = A_(S);     // STO
  float* B64b = A_(S);     // CL
  float* wtmbl[3]; for (int li = 0; li < 3; ++li) wtmbl[li] = A_(8192);
  float* wtwl = A_(1024);
  unsigned short* warena = (unsigned short*)(ws + off);

  size_t wOff = 0;
  auto alloc = [&](int taps, int KS) {
    size_t o = wOff;
    wOff += (size_t)2 * taps * KS * 2048;
    return o;
  };
  size_t oSTH0n = alloc(25, 1), oSTH0h = alloc(25, 4);
  size_t oSTH1n = alloc(25, 1), oSTH1h = alloc(25, 4);
  size_t oSTM0n = alloc(25, 1), oSTM0m = alloc(25, 4);
  size_t oSTM1n = alloc(25, 1), oSTM1m = alloc(25, 4);
  size_t oSTOa = alloc(25, 4), oSTOb = alloc(25, 4);
  size_t oCLa = alloc(1, 4), oCLb = alloc(1, 4);
  size_t oMNa0[3], oMNa1[3], oMNb0[3], oMNb1[3], oS0[3], oS1[3], oT0[3], oT1[3],
      oX0[3], oX1[3], oMH0[3], oMH1[3], oMX0[3], oMX1[3];
  for (int li = 0; li < 3; ++li) {
    oMNa0[li] = alloc(25, 4); oMNa1[li] = alloc(25, 4);
    oMNb0[li] = alloc(25, 4); oMNb1[li] = alloc(25, 4);
    oS0[li] = alloc(25, 4); oS1[li] = alloc(25, 4);
    oT0[li] = alloc(25, 4); oT1[li] = alloc(25, 4);
    oX0[li] = alloc(25, 4); oX1[li] = alloc(25, 4);
    oMH0[li] = alloc(25, 4); oMH1[li] = alloc(25, 4);
    oMX0[li] = alloc(25, 4); oMX1[li] = alloc(25, 4);
  }
  if (ws_size < off * sizeof(float) + wOff * sizeof(unsigned short)) return;

  hipMemsetAsync(ws, 0, zeroFloats * sizeof(float), stream);
  hipMemsetAsync(warena, 0, wOff * sizeof(unsigned short), stream);

  auto packL = [&](size_t dstOff, const float* src, int srcRow0, int nRows,
                   int dstRow0, int ciBase, int cinSrc, int taps, int KS) {
    int total = taps * KS * 4 * 64;
    pack_k<<<(total + 255) / 256, 256, 0, stream>>>(warena + dstOff, src, srcRow0,
                                                    nRows, dstRow0, ciBase, cinSrc,
                                                    taps, KS);
  };
  // st_cx rows: i(0) f(64) g(128) i'(192) f'(256) g'(320) o(384)
  packL(oSTH0n, st_cx, 0, 128, 0, 0, 16, 25, 1);
  packL(oSTH0h, st_ch, 0, 128, 0, 0, 64, 25, 4);
  packL(oSTH1n, st_cx, 128, 64, 0, 0, 16, 25, 1);
  packL(oSTH1n, st_cx, 384, 64, 64, 0, 16, 25, 1);
  packL(oSTH1h, st_ch, 128, 128, 0, 0, 64, 25, 4);
  packL(oSTM0n, st_cx, 192, 128, 0, 0, 16, 25, 1);
  packL(oSTM0m, st_cm, 0, 128, 0, 0, 64, 25, 4);
  packL(oSTM1n, st_cx, 320, 64, 0, 0, 16, 25, 1);
  packL(oSTM1m, st_cm, 128, 64, 0, 0, 64, 25, 4);
  packL(oSTOa, st_co, 0, 64, 0, 0, 128, 25, 4);
  packL(oSTOb, st_co, 0, 64, 0, 64, 128, 25, 4);
  packL(oCLa, st_cl, 0, 64, 0, 0, 128, 1, 4);
  packL(oCLb, st_cl, 0, 64, 0, 64, 128, 1, 4);
  for (int li = 0; li < 3; ++li) {
    const float* ch = mn_ch + (size_t)li * 409600;
    const float* cx = mn_cx + (size_t)li * 409600;
    const float* mbs = mb_s + (size_t)li * 409600;
    const float* mbt = mb_t + (size_t)li * 307200;
    const float* mbx = mb_x + (size_t)li * 409600;
    const float* mmh = mb_mh + (size_t)li * 409600;
    const float* mmx = mb_mx + (size_t)li * 409600;
    packL(oMNa0[li], ch, 0, 128, 0, 0, 64, 25, 4);
    packL(oMNa1[li], ch, 128, 128, 0, 0, 64, 25, 4);
    packL(oMNb0[li], cx, 0, 128, 0, 0, 64, 25, 4);
    packL(oMNb1[li], cx, 128, 128, 0, 0, 64, 25, 4);
    packL(oS0[li], mbs, 0, 128, 0, 0, 64, 25, 4);
    packL(oS1[li], mbs, 128, 128, 0, 0, 64, 25, 4);
    packL(oT0[li], mbt, 0, 128, 0, 0, 64, 25, 4);
    packL(oT1[li], mbt, 128, 64, 0, 0, 64, 25, 4);
    packL(oX0[li], mbx, 0, 128, 0, 0, 64, 25, 4);
    packL(oX1[li], mbx, 128, 128, 0, 0, 64, 25, 4);
    packL(oMH0[li], mmh, 0, 128, 0, 0, 64, 25, 4);
    packL(oMH1[li], mmh, 128, 128, 0, 0, 64, 25, 4);
    packL(oMX0[li], mmx, 0, 128, 0, 0, 64, 25, 4);
    packL(oMX1[li], mmx, 128, 128, 0, 0, 64, 25, 4);
    tr1_k<<<32, 256, 0, stream>>>(mb_last + (size_t)li * 8192, wtmbl[li], 128, 64);
  }
  tr1_k<<<4, 256, 0, stream>>>(w_last, wtwl, 64, 16);

  auto mkj = [&](const float* x0, size_t w0, int cin0, const float* x1, size_t w1,
                 int cin1, int taps, float* o, int outCo, int coBase, int coCnt) {
    Job j;
    j.x0 = x0; j.w0 = warena + w0; j.cin0 = cin0;
    j.x1 = x1; j.w1 = warena + w1; j.cin1 = cin1;
    j.taps = taps; j.out = o; j.outCo = outCo; j.coBase = coBase; j.coCnt = coCnt;
    j.blockStart = 0;
    return j;
  };
  auto launchB = [&](Batch& bt) {
    int nb = 0;
    for (int q = 0; q < bt.n; ++q) { bt.j[q].blockStart = nb; nb += 32; }
    convmf5_k<<<nb, 256, 0, stream>>>(bt);
  };

  for (int t = 0; t < 19; ++t) {
    const float* stIn = (t < 10) ? netb : xgen;
    if (t < 10) build_net_k<<<512, 256, 0, stream>>>(frames0, netb, t);
    {
      Batch P; P.n = 4;
      P.j[0] = mkj(stIn, oSTH0n, 16, hs[0], oSTH0h, 64, 25, R1, 256, 0, 128);
      P.j[1] = mkj(stIn, oSTH1n, 16, hs[0], oSTH1h, 64, 25, R1, 256, 128, 128);
      P.j[2] = mkj(stIn, oSTM0n, 16, memb, oSTM0m, 64, 25, R2, 192, 0, 128);
      P.j[3] = mkj(stIn, oSTM1n, 16, memb, oSTM1m, 64, 25, R2, 192, 128, 64);
      launchB(P);
    }
    st_gate1_k<<<2048, 256, 0, stream>>>(R1, R2, cs[0], memb);
    {
      Batch P; P.n = 2;
      P.j[0] = mkj(cs[0], oSTOa, 64, memb, oSTOb, 64, 25, B64a, 64, 0, 64);
      P.j[1] = mkj(cs[0], oCLa, 64, memb, oCLb, 64, 1, B64b, 64, 0, 64);
      launchB(P);
    }
    st_gate2_k<<<2048, 256, 0, stream>>>(R1, B64a, B64b, hs[0], diffb);

    for (int i = 1; i < 4; ++i) {
      int li = i - 1;
      const float* din = (i == 1) ? diffb : dh[i - 2];
      {
        Batch P; int n = 0;
        if (t >= 1) {
          P.j[n++] = mkj(dh[li], oMNa0[li], 64, din, oMNb0[li], 64, 25, R1, 256, 0, 128);
          P.j[n++] = mkj(dh[li], oMNa1[li], 64, din, oMNb1[li], 64, 25, R1, 256, 128, 128);
        }
        P.j[n++] = mkj(memb, oS0[li], 64, nullptr, oS0[li], 0, 25, R5, 256, 0, 128);
        P.j[n++] = mkj(memb, oS1[li], 64, nullptr, oS1[li], 0, 25, R5, 256, 128, 128);
        P.j[n++] = mkj(hs[i - 1], oX0[li], 64, nullptr, oX0[li], 0, 25, R3, 256, 0, 128);
        P.j[n++] = mkj(hs[i - 1], oX1[li], 64, nullptr, oX1[li], 0, 25, R3, 256, 128, 128);
        P.j[n++] = mkj(hs[i], oT0[li], 64, nullptr, oT0[li], 0, 25, R2, 192, 0, 128);
        P.j[n++] = mkj(hs[i], oT1[li], 64, nullptr, oT1[li], 0, 25, R2, 192, 128, 64);
        P.j[n++] = mkj(cs[i], oMH0[li], 64, nullptr, oMH0[li], 0, 25, RM, 256, 0, 128);
        P.j[n++] = mkj(cs[i], oMH1[li], 64, nullptr, oMH1[li], 0, 25, RM, 256, 128, 128);
        P.n = n;
        launchB(P);
      }
      if (t >= 1)
        mimn_gate_k<<<2048, 256, 0, stream>>>(R1, dh[li], dcb[li],
                                              mn_ctw + (size_t)li * 131072,
                                              mn_ocw + (size_t)li * 65536);
      {
        Batch P; P.n = 2;
        P.j[0] = mkj(dh[li], oMX0[li], 64, nullptr, oMX0[li], 0, 25, R1, 256, 0, 128);
        P.j[1] = mkj(dh[li], oMX1[li], 64, nullptr, oMX1[li], 0, 25, R1, 256, 128, 128);
        launchB(P);
      }
      mb_gate1_k<<<2048, 256, 0, stream>>>(R5, R2, R3, RM, R1, memb, cs[i], ccb[li],
                                           mb_ctw + (size_t)li * 131072,
                                           mb_ocw + (size_t)li * 65536);
      mb_gate2c1_k<<<128, 256, 0, stream>>>(cs[i], memb, wtmbl[li], R5, R2, R3, hs[i]);
    }
    xgen_k<<<32, 256, 0, stream>>>(hs[3], wtwl, xgen, out, t);
  }
}

// Round 8
// 16778.568 us; speedup vs baseline: 1.3990x; 1.2321x over previous
//
#include <hip/hip_runtime.h>
#include <math.h>

// ---------------------------------------------------------------------------
// MIM RNN round 7: convmf3 (best) + XCD-aware job placement: job = blk % n
// so each job's 32 blocks land on a fixed XCD subset -> weights stay in the
// 4MB per-XCD L2. Split-bf16 (3 merged passes), depth-2 A ping-pong.
// ---------------------------------------------------------------------------

#define S 524288  // 8*64*1024

typedef __attribute__((ext_vector_type(8))) short bf16x8;
typedef __attribute__((ext_vector_type(16))) float f32x16;

__device__ __forceinline__ float sigf(float x) { return 1.0f / (1.0f + expf(-x)); }
__device__ __forceinline__ unsigned short f2bf(float f) {
  unsigned u = __float_as_uint(f);
  u += 0x7fffu + ((u >> 16) & 1u);
  return (unsigned short)(u >> 16);
}
__device__ __forceinline__ float bf2f(unsigned short h) {
  return __uint_as_float(((unsigned)h) << 16);
}

struct Job {
  const float* x0; const unsigned short* w0; int cin0;
  const float* x1; const unsigned short* w1; int cin1;
  int taps; float* out; int outCo; int coBase; int coCnt;
};
struct Batch { Job j[8]; int n; };

// ---------------------------------------------------------------------------
// Weight prepack: W'[half][tap][ks][coB4][lane64][8] bf16.
__global__ void pack_k(unsigned short* dst, const float* src, int srcRow0,
                       int nRows, int dstRow0, int ciBase, int cinSrc, int taps,
                       int KS) {
  int idx = blockIdx.x * 256 + threadIdx.x;
  int total = taps * KS * 4 * 64;
  if (idx >= total) return;
  int l = idx & 63;
  int cb = (idx >> 6) & 3;
  int rest = idx >> 8;
  int ks = rest % KS, tap = rest / KS;
  int co_d = cb * 32 + (l & 31);
  if (co_d < dstRow0 || co_d >= dstRow0 + nRows) return;
  int srcRow = srcRow0 + (co_d - dstRow0);
  size_t AH = (size_t)taps * KS * 2048;
  size_t base = ((size_t)(tap * KS + ks) * 4 + cb) * 512 + (size_t)l * 8;
#pragma unroll
  for (int j = 0; j < 8; ++j) {
    int ci = ciBase + ks * 16 + (l >> 5) * 8 + j;
    float v = src[((size_t)srcRow * cinSrc + ci) * taps + tap];
    unsigned short hi = f2bf(v);
    unsigned short lo = f2bf(v - bf2f(hi));
    dst[base + j] = hi;
    dst[AH + base + j] = lo;
  }
}

__global__ void tr1_k(const float* __restrict__ src, float* __restrict__ dst,
                      int Cin, int Cout) {
  int idx = blockIdx.x * 256 + threadIdx.x;
  if (idx >= Cout * Cin) return;
  int ci = idx % Cin, co = idx / Cin;
  dst[(size_t)ci * Cout + co] = src[idx];
}

// ---------------------------------------------------------------------------
// Conv: block = 128co x 256px (8 img rows), 4 waves; wave = 2 co-tiles x 4
// px-row-tiles. Slice = (tap,kk): 4 A-frags + 8 B LDS reads + 24 MFMAs;
// A ping-pong prefetched 2 slices ahead. Job decode: blk % n -> XCD-resident.
__global__ __launch_bounds__(256, 2) void convmf3_k(Batch bt) {
  int blk = blockIdx.x;
  int ji = blk % bt.n;
  int local = blk / bt.n;
  Job J = bt.j[ji];
  int pxg = local & 3;
  int b = local >> 2;
  int r0 = pxg * 8;
  int tid = threadIdx.x, l = tid & 63, wv = tid >> 6;
  int wc = wv & 1, wr = wv >> 1;
  int lcol = l & 31, lg = l >> 5;

  // B-tile: [half][12 rows][36 cols x 64B]; 32 ci per (row,col) in 4
  // XOR-swizzled 16B slots. Row stride 2368B.
  __shared__ __align__(16) unsigned char lds[2][12][2368];

  f32x16 acc[2][4];
#pragma unroll
  for (int r = 0; r < 2; ++r)
#pragma unroll
    for (int j2 = 0; j2 < 4; ++j2)
#pragma unroll
      for (int q = 0; q < 16; ++q) acc[r][j2][q] = 0.f;

  {  // zero halo cols 0,1,34,35 once (disjoint from staged cols 2..33)
    int e = tid;
#pragma unroll
    for (int it = 0; it < 2; ++it, e += 256)
      if (e < 384) {
        int hh = e & 1, sl = (e >> 1) & 3;
        int rq = e >> 3;
        int row = rq % 12, cq = rq / 12;
        int col = cq < 2 ? cq : 32 + cq;
        float4 z = {0.f, 0.f, 0.f, 0.f};
        *(float4*)&lds[hh][row][col * 64 + sl * 16] = z;
      }
  }

  for (int s = 0; s < 2; ++s) {
    const float* X = s ? J.x1 : J.x0;
    const unsigned short* W = s ? J.w1 : J.w0;
    int cin = s ? J.cin1 : J.cin0;
    if (cin == 0) continue;
    int KS = cin >> 4;
    size_t AH = (size_t)J.taps * KS * 2048;
    int nst = (cin + 31) >> 5;
    for (int st = 0; st < nst; ++st) {
      int ciCnt = cin - st * 32;
      if (ciCnt > 32) ciCnt = 32;
      int kls = ciCnt >> 4;      // 1 or 2
      int kshift = kls >> 1;     // 0 or 1
      int NS = J.taps * kls;
      auto aaddr = [&](int u) {
        int tap = u >> kshift, kk = u & (kls - 1);
        return W + (((size_t)tap * KS + st * 2 + kk) * 4 + wc * 2) * 512 +
               (size_t)l * 8;
      };
      // A prologue (issued BEFORE barriers: flies under LDS staging)
      bf16x8 pah0, pah1, pal0, pal1, pbh0, pbh1, pbl0, pbl1;
      {
        const unsigned short* wp = aaddr(0);
        pah0 = *(const bf16x8*)wp;
        pah1 = *(const bf16x8*)(wp + 512);
        pal0 = *(const bf16x8*)(wp + AH);
        pal1 = *(const bf16x8*)(wp + AH + 512);
      }
      if (NS > 1) {
        const unsigned short* wp = aaddr(1);
        pbh0 = *(const bf16x8*)wp;
        pbh1 = *(const bf16x8*)(wp + 512);
        pbl0 = *(const bf16x8*)(wp + AH);
        pbl1 = *(const bf16x8*)(wp + AH + 512);
      }
      __syncthreads();
      // stage 12 rows (r0-2 .. r0+9) of up-to-32 ci, hi+lo halves
      for (int u = tid; u < 1536; u += 256) {
        int cp = u & 15;
        int xq = (u >> 4) & 7;
        int row = u >> 7;  // 0..11
        if (2 * cp < ciCnt) {
          int gy = r0 - 2 + row;
          float4 v0 = {0.f, 0.f, 0.f, 0.f}, v1 = {0.f, 0.f, 0.f, 0.f};
          if ((unsigned)gy < 32u) {
            const float* p0 =
                X + (((size_t)b * cin + st * 32 + 2 * cp) << 10) + gy * 32 + xq * 4;
            v0 = *(const float4*)p0;
            v1 = *(const float4*)(p0 + 1024);
          }
          const float* e0 = (const float*)&v0;
          const float* e1 = (const float*)&v1;
          int slot = cp >> 2, boff = (cp & 3) * 4;
#pragma unroll
          for (int e = 0; e < 4; ++e) {
            int col = xq * 4 + 2 + e;
            int off2 = col * 64 + ((slot ^ ((col >> 1) & 3)) << 4) + boff;
            unsigned short h0 = f2bf(e0[e]);
            unsigned short h1 = f2bf(e1[e]);
            unsigned short lo0 = f2bf(e0[e] - bf2f(h0));
            unsigned short lo1 = f2bf(e1[e] - bf2f(h1));
            *(unsigned*)&lds[0][row][off2] = (unsigned)h0 | ((unsigned)h1 << 16);
            *(unsigned*)&lds[1][row][off2] = (unsigned)lo0 | ((unsigned)lo1 << 16);
          }
        }
      }
      __syncthreads();
      auto slice = [&](int u, bf16x8 ah0, bf16x8 ah1, bf16x8 al0, bf16x8 al1) {
        int tap = u >> kshift, kk = u & (kls - 1);
        int dy, dx;
        if (J.taps == 1) { dy = 2; dx = 2; }
        else { dy = tap / 5; dx = tap - dy * 5; }
        int col = lcol + dx, cOff = col * 64, swz = (col >> 1) & 3;
        int phys = (((kk * 2 + lg) ^ swz) << 4);
        bf16x8 bb[4];
#pragma unroll
        for (int j2 = 0; j2 < 4; ++j2)
          bb[j2] = *(const bf16x8*)&lds[0][wr * 4 + j2 + dy][cOff + phys];
#pragma unroll
        for (int j2 = 0; j2 < 4; ++j2) {
          acc[0][j2] = __builtin_amdgcn_mfma_f32_32x32x16_bf16(ah0, bb[j2], acc[0][j2], 0, 0, 0);
          acc[1][j2] = __builtin_amdgcn_mfma_f32_32x32x16_bf16(ah1, bb[j2], acc[1][j2], 0, 0, 0);
        }
#pragma unroll
        for (int j2 = 0; j2 < 4; ++j2) {
          acc[0][j2] = __builtin_amdgcn_mfma_f32_32x32x16_bf16(al0, bb[j2], acc[0][j2], 0, 0, 0);
          acc[1][j2] = __builtin_amdgcn_mfma_f32_32x32x16_bf16(al1, bb[j2], acc[1][j2], 0, 0, 0);
        }
        // overwrite bb with lo-half of B (pass 3 = ah * bl)
#pragma unroll
        for (int j2 = 0; j2 < 4; ++j2)
          bb[j2] = *(const bf16x8*)(&lds[0][wr * 4 + j2 + dy][cOff + phys] + 12 * 2368);
#pragma unroll
        for (int j2 = 0; j2 < 4; ++j2) {
          acc[0][j2] = __builtin_amdgcn_mfma_f32_32x32x16_bf16(ah0, bb[j2], acc[0][j2], 0, 0, 0);
          acc[1][j2] = __builtin_amdgcn_mfma_f32_32x32x16_bf16(ah1, bb[j2], acc[1][j2], 0, 0, 0);
        }
      };
      for (int uu = 0; uu < NS; uu += 2) {
        slice(uu, pah0, pah1, pal0, pal1);
        if (uu + 2 < NS) {
          const unsigned short* wp = aaddr(uu + 2);
          pah0 = *(const bf16x8*)wp;
          pah1 = *(const bf16x8*)(wp + 512);
          pal0 = *(const bf16x8*)(wp + AH);
          pal1 = *(const bf16x8*)(wp + AH + 512);
        }
        if (uu + 1 < NS) {
          slice(uu + 1, pbh0, pbh1, pbl0, pbl1);
          if (uu + 3 < NS) {
            const unsigned short* wp = aaddr(uu + 3);
            pbh0 = *(const bf16x8*)wp;
            pbh1 = *(const bf16x8*)(wp + 512);
            pbl0 = *(const bf16x8*)(wp + AH);
            pbl1 = *(const bf16x8*)(wp + AH + 512);
          }
        }
      }
    }
  }
  // store: D col = lane&31 (px), row = (reg&3) + 8*(reg>>2) + 4*(lane>>5)
#pragma unroll
  for (int r = 0; r < 2; ++r) {
#pragma unroll
    for (int j2 = 0; j2 < 4; ++j2) {
      int prow = r0 + wr * 4 + j2;
      float* op = J.out + (((size_t)b * J.outCo) << 10) + prow * 32 + lcol;
#pragma unroll
      for (int q = 0; q < 16; ++q) {
        int coLoc = wc * 64 + r * 32 + 4 * lg + (q & 3) + 8 * (q >> 2);
        if (coLoc < J.coCnt)
          op[(size_t)(J.coBase + coLoc) << 10] = acc[r][j2][q];
      }
    }
  }
}

// ---------------------------------------------------------------------------
__global__ void build_net_k(const float* __restrict__ frames0, float* __restrict__ net,
                            int t) {
  int idx = blockIdx.x * 256 + threadIdx.x;
  int b = idx >> 14, ch = (idx >> 10) & 15, p = idx & 1023;
  int y = p >> 5, x = p & 31, py = ch >> 2, px = ch & 3;
  net[idx] = frames0[((size_t)b * 10 + t) * 16384 + (y * 4 + py) * 128 + (x * 4 + px)];
}

// STH [b][256]: i,f,g,o ; STM [b][192]: i',f',g'
__global__ void st_gate1_k(const float* __restrict__ sth, const float* __restrict__ stm,
                           float* __restrict__ c, float* __restrict__ m) {
  int idx = blockIdx.x * 256 + threadIdx.x;
  int b = idx >> 16, r = idx & 65535;
  const float* hb = sth + (size_t)b * 262144 + r;
  const float* mb = stm + (size_t)b * 196608 + r;
  float cn = sigf(hb[65536] + 1.f) * c[idx] + sigf(hb[0]) * tanhf(hb[131072]);
  float mn = sigf(mb[65536] + 1.f) * m[idx] + sigf(mb[0]) * tanhf(mb[131072]);
  c[idx] = cn;
  m[idx] = mn;
}

__global__ void st_gate2_k(const float* __restrict__ sth, const float* __restrict__ oS,
                           const float* __restrict__ cl, float* __restrict__ h,
                           float* __restrict__ diff) {
  int idx = blockIdx.x * 256 + threadIdx.x;
  int b = idx >> 16, r = idx & 65535;
  float o = sigf(sth[(size_t)b * 262144 + 196608 + r] + oS[idx]);
  float hn = o * tanhf(cl[idx]);
  float old = h[idx];
  h[idx] = hn;
  diff[idx] = hn - old;
}

// merged MN conv output: chunks i,g,f,o
__global__ void mimn_gate_k(const float* __restrict__ MN, float* __restrict__ dh,
                            float* __restrict__ dc, const float* __restrict__ ctw,
                            const float* __restrict__ ocw) {
  int idx = blockIdx.x * 256 + threadIdx.x;
  int b = idx >> 16, r = idx & 65535;
  const float* q = MN + (size_t)b * 262144 + r;
  float c0 = dc[idx];
  float cn = sigf(q[131072] + c0 * ctw[65536 + r] + 1.f) * c0 +
             sigf(q[0] + c0 * ctw[r]) * tanhf(q[65536]);
  float hn = sigf(q[196608] + cn * ocw[r]) * tanhf(cn);
  dc[idx] = cn;
  dh[idx] = hn;
}

// S:i,g,f,o  T:i,g,o  X:i,g,f,o  QH/QX:i,g,f,o (summed)
__global__ void mb_gate1_k(const float* __restrict__ Sb, const float* __restrict__ Tb,
                           const float* __restrict__ Xb, const float* __restrict__ QH,
                           const float* __restrict__ QX, float* __restrict__ m,
                           float* __restrict__ c, float* __restrict__ cc,
                           const float* __restrict__ ctw, const float* __restrict__ ocw) {
  int idx = blockIdx.x * 256 + threadIdx.x;
  int b = idx >> 16, r = idx & 65535;
  const float* sb = Sb + (size_t)b * 262144 + r;
  const float* tb = Tb + (size_t)b * 196608 + r;
  const float* xb = Xb + (size_t)b * 262144 + r;
  const float* qh = QH + (size_t)b * 262144 + r;
  const float* qx = QX + (size_t)b * 262144 + r;
  float i_s = sb[0], g_s = sb[65536], f_s = sb[131072];
  float i_t = tb[0], g_t = tb[65536];
  float i_x = xb[0], g_x = xb[65536], f_x = xb[131072];
  float m0 = m[idx];
  float nm = sigf(f_x + f_s + 1.f) * m0 + sigf(i_x + i_s) * tanhf(g_x + g_s);
  float q_i = qh[0] + qx[0], q_g = qh[65536] + qx[65536];
  float q_f = qh[131072] + qx[131072], q_o = qh[196608] + qx[196608];
  float cc0 = cc[idx];
  float mims = sigf(q_f + cc0 * ctw[65536 + r] + 1.f) * cc0 +
               sigf(q_i + cc0 * ctw[r]) * tanhf(q_g);
  float h2 = sigf(q_o + mims * ocw[r]) * tanhf(mims);
  float nc = h2 + sigf(i_x + i_t) * tanhf(g_x + g_t);
  m[idx] = nm;
  c[idx] = nc;
  cc[idx] = mims;
}

// fused conv1(mb_last over [cI,m0]) + 3-term output gate. grid 128
__global__ __launch_bounds__(256) void mb_gate2c1_k(
    const float* __restrict__ cI, const float* __restrict__ m0,
    const float* __restrict__ wl, const float* __restrict__ Sb,
    const float* __restrict__ Tb, const float* __restrict__ Xb,
    float* __restrict__ h) {
  int blk = blockIdx.x;
  int coB = blk & 3, pb = (blk >> 2) & 3, b = blk >> 4;
  int tid = threadIdx.x, px = pb * 256 + tid;
  float acc[16];
#pragma unroll
  for (int c = 0; c < 16; ++c) acc[c] = 0.f;
  const float* ib1 = cI + (size_t)b * 65536 + px;
  const float* ib2 = m0 + (size_t)b * 65536 + px;
  for (int ci = 0; ci < 64; ++ci) {
    float v1 = ib1[ci * 1024], v2 = ib2[ci * 1024];
    const float* w1 = wl + (size_t)ci * 64 + coB * 16;
    const float* w2 = wl + (size_t)(64 + ci) * 64 + coB * 16;
#pragma unroll
    for (int c = 0; c < 16; ++c) {
      acc[c] = fmaf(w1[c], v1, acc[c]);
      acc[c] = fmaf(w2[c], v2, acc[c]);
    }
  }
#pragma unroll
  for (int c = 0; c < 16; ++c) {
    int co = coB * 16 + c;
    size_t o = (size_t)co * 1024 + px;
    float osum = Xb[(size_t)b * 262144 + 196608 + o] +
                 Tb[(size_t)b * 196608 + 131072 + o] +
                 Sb[(size_t)b * 262144 + 196608 + o];
    h[(size_t)b * 65536 + o] = sigf(osum) * tanhf(acc[c]);
  }
}

// final conv1 w_last + unpatchify. grid 32
__global__ __launch_bounds__(256) void xgen_k(const float* __restrict__ h3,
                                              const float* __restrict__ wwl,
                                              float* __restrict__ xg,
                                              float* __restrict__ out, int t) {
  int blk = blockIdx.x;
  int pb = blk & 3, b = blk >> 2;
  int tid = threadIdx.x, px = pb * 256 + tid;
  float acc[16];
#pragma unroll
  for (int c = 0; c < 16; ++c) acc[c] = 0.f;
  const float* ib = h3 + (size_t)b * 65536 + px;
  for (int ci = 0; ci < 64; ++ci) {
    float v = ib[ci * 1024];
    const float* w = wwl + (size_t)ci * 16;
#pragma unroll
    for (int c = 0; c < 16; ++c) acc[c] = fmaf(w[c], v, acc[c]);
  }
  int y = px >> 5, x = px & 31;
#pragma unroll
  for (int c = 0; c < 16; ++c) {
    xg[(size_t)b * 16384 + (size_t)c * 1024 + px] = acc[c];
    if (t >= 9) {
      int py = c >> 2, pxs = c & 3;
      out[((size_t)b * 10 + (t - 9)) * 16384 + (y * 4 + py) * 128 + (x * 4 + pxs)] =
          acc[c];
    }
  }
}

// ---------------------------------------------------------------------------
extern "C" void kernel_launch(void* const* d_in, const int* in_sizes, int n_in,
                              void* d_out, int out_size, void* d_ws, size_t ws_size,
                              hipStream_t stream) {
  const float* frames0 = (const float*)d_in[0];
  const float* st_cx = (const float*)d_in[2];
  const float* st_ch = (const float*)d_in[3];
  const float* st_cm = (const float*)d_in[4];
  const float* st_co = (const float*)d_in[5];
  const float* st_cl = (const float*)d_in[6];
  const float* mb_t = (const float*)d_in[7];
  const float* mb_s = (const float*)d_in[8];
  const float* mb_x = (const float*)d_in[9];
  const float* mb_mh = (const float*)d_in[10];
  const float* mb_mx = (const float*)d_in[11];
  const float* mb_ctw = (const float*)d_in[12];
  const float* mb_ocw = (const float*)d_in[13];
  const float* mb_last = (const float*)d_in[14];
  const float* mn_ch = (const float*)d_in[15];
  const float* mn_cx = (const float*)d_in[16];
  const float* mn_ctw = (const float*)d_in[17];
  const float* mn_ocw = (const float*)d_in[18];
  const float* w_last = (const float*)d_in[19];
  float* out = (float*)d_out;

  float* ws = (float*)d_ws;
  size_t off = 0;
  auto A_ = [&](size_t n) { float* p = ws + off; off += n; return p; };
  float* hs[4]; for (int i = 0; i < 4; ++i) hs[i] = A_(S);
  float* cs[4]; for (int i = 0; i < 4; ++i) cs[i] = A_(S);
  float* memb = A_(S);
  float* dh[3]; for (int i = 0; i < 3; ++i) dh[i] = A_(S);
  float* dcb[3]; for (int i = 0; i < 3; ++i) dcb[i] = A_(S);
  float* ccb[3]; for (int i = 0; i < 3; ++i) ccb[i] = A_(S);
  float* diffb = A_(S);
  size_t zeroFloats = off;  // 19*S
  float* xgen = A_(131072);
  float* netb = A_(131072);
  float* R1 = A_(4 * S);   // STH / MN / QX
  float* R2 = A_(3 * S);   // STM / T
  float* R3 = A_(4 * S);   // X
  float* R5 = A_(4 * S);   // S
  float* RM = A_(4 * S);   // MH (QH)
  float* B64a = A_(S);     // STO
  float* B64b = A_(S);     // CL
  float* wtmbl[3]; for (int li = 0; li < 3; ++li) wtmbl[li] = A_(8192);
  float* wtwl = A_(1024);
  unsigned short* warena = (unsigned short*)(ws + off);

  size_t wOff = 0;
  auto alloc = [&](int taps, int KS) {
    size_t o = wOff;
    wOff += (size_t)2 * taps * KS * 2048;
    return o;
  };
  size_t oSTH0n = alloc(25, 1), oSTH0h = alloc(25, 4);
  size_t oSTH1n = alloc(25, 1), oSTH1h = alloc(25, 4);
  size_t oSTM0n = alloc(25, 1), oSTM0m = alloc(25, 4);
  size_t oSTM1n = alloc(25, 1), oSTM1m = alloc(25, 4);
  size_t oSTOa = alloc(25, 4), oSTOb = alloc(25, 4);
  size_t oCLa = alloc(1, 4), oCLb = alloc(1, 4);
  size_t oMNa0[3], oMNa1[3], oMNb0[3], oMNb1[3], oS0[3], oS1[3], oT0[3], oT1[3],
      oX0[3], oX1[3], oMH0[3], oMH1[3], oMX0[3], oMX1[3];
  for (int li = 0; li < 3; ++li) {
    oMNa0[li] = alloc(25, 4); oMNa1[li] = alloc(25, 4);
    oMNb0[li] = alloc(25, 4); oMNb1[li] = alloc(25, 4);
    oS0[li] = alloc(25, 4); oS1[li] = alloc(25, 4);
    oT0[li] = alloc(25, 4); oT1[li] = alloc(25, 4);
    oX0[li] = alloc(25, 4); oX1[li] = alloc(25, 4);
    oMH0[li] = alloc(25, 4); oMH1[li] = alloc(25, 4);
    oMX0[li] = alloc(25, 4); oMX1[li] = alloc(25, 4);
  }
  if (ws_size < off * sizeof(float) + wOff * sizeof(unsigned short)) return;

  hipMemsetAsync(ws, 0, zeroFloats * sizeof(float), stream);
  hipMemsetAsync(warena, 0, wOff * sizeof(unsigned short), stream);

  auto packL = [&](size_t dstOff, const float* src, int srcRow0, int nRows,
                   int dstRow0, int ciBase, int cinSrc, int taps, int KS) {
    int total = taps * KS * 4 * 64;
    pack_k<<<(total + 255) / 256, 256, 0, stream>>>(warena + dstOff, src, srcRow0,
                                                    nRows, dstRow0, ciBase, cinSrc,
                                                    taps, KS);
  };
  // st_cx rows: i(0) f(64) g(128) i'(192) f'(256) g'(320) o(384)
  packL(oSTH0n, st_cx, 0, 128, 0, 0, 16, 25, 1);
  packL(oSTH0h, st_ch, 0, 128, 0, 0, 64, 25, 4);
  packL(oSTH1n, st_cx, 128, 64, 0, 0, 16, 25, 1);
  packL(oSTH1n, st_cx, 384, 64, 64, 0, 16, 25, 1);
  packL(oSTH1h, st_ch, 128, 128, 0, 0, 64, 25, 4);
  packL(oSTM0n, st_cx, 192, 128, 0, 0, 16, 25, 1);
  packL(oSTM0m, st_cm, 0, 128, 0, 0, 64, 25, 4);
  packL(oSTM1n, st_cx, 320, 64, 0, 0, 16, 25, 1);
  packL(oSTM1m, st_cm, 128, 64, 0, 0, 64, 25, 4);
  packL(oSTOa, st_co, 0, 64, 0, 0, 128, 25, 4);
  packL(oSTOb, st_co, 0, 64, 0, 64, 128, 25, 4);
  packL(oCLa, st_cl, 0, 64, 0, 0, 128, 1, 4);
  packL(oCLb, st_cl, 0, 64, 0, 64, 128, 1, 4);
  for (int li = 0; li < 3; ++li) {
    const float* ch = mn_ch + (size_t)li * 409600;
    const float* cx = mn_cx + (size_t)li * 409600;
    const float* mbs = mb_s + (size_t)li * 409600;
    const float* mbt = mb_t + (size_t)li * 307200;
    const float* mbx = mb_x + (size_t)li * 409600;
    const float* mmh = mb_mh + (size_t)li * 409600;
    const float* mmx = mb_mx + (size_t)li * 409600;
    packL(oMNa0[li], ch, 0, 128, 0, 0, 64, 25, 4);
    packL(oMNa1[li], ch, 128, 128, 0, 0, 64, 25, 4);
    packL(oMNb0[li], cx, 0, 128, 0, 0, 64, 25, 4);
    packL(oMNb1[li], cx, 128, 128, 0, 0, 64, 25, 4);
    packL(oS0[li], mbs, 0, 128, 0, 0, 64, 25, 4);
    packL(oS1[li], mbs, 128, 128, 0, 0, 64, 25, 4);
    packL(oT0[li], mbt, 0, 128, 0, 0, 64, 25, 4);
    packL(oT1[li], mbt, 128, 64, 0, 0, 64, 25, 4);
    packL(oX0[li], mbx, 0, 128, 0, 0, 64, 25, 4);
    packL(oX1[li], mbx, 128, 128, 0, 0, 64, 25, 4);
    packL(oMH0[li], mmh, 0, 128, 0, 0, 64, 25, 4);
    packL(oMH1[li], mmh, 128, 128, 0, 0, 64, 25, 4);
    packL(oMX0[li], mmx, 0, 128, 0, 0, 64, 25, 4);
    packL(oMX1[li], mmx, 128, 128, 0, 0, 64, 25, 4);
    tr1_k<<<32, 256, 0, stream>>>(mb_last + (size_t)li * 8192, wtmbl[li], 128, 64);
  }
  tr1_k<<<4, 256, 0, stream>>>(w_last, wtwl, 64, 16);

  auto mkj = [&](const float* x0, size_t w0, int cin0, const float* x1, size_t w1,
                 int cin1, int taps, float* o, int outCo, int coBase, int coCnt) {
    Job j;
    j.x0 = x0; j.w0 = warena + w0; j.cin0 = cin0;
    j.x1 = x1; j.w1 = warena + w1; j.cin1 = cin1;
    j.taps = taps; j.out = o; j.outCo = outCo; j.coBase = coBase; j.coCnt = coCnt;
    return j;
  };
  auto launchB = [&](Batch& bt) {
    convmf3_k<<<bt.n * 32, 256, 0, stream>>>(bt);
  };

  for (int t = 0; t < 19; ++t) {
    const float* stIn = (t < 10) ? netb : xgen;
    if (t < 10) build_net_k<<<512, 256, 0, stream>>>(frames0, netb, t);
    {
      Batch P; P.n = 4;
      P.j[0] = mkj(stIn, oSTH0n, 16, hs[0], oSTH0h, 64, 25, R1, 256, 0, 128);
      P.j[1] = mkj(stIn, oSTH1n, 16, hs[0], oSTH1h, 64, 25, R1, 256, 128, 128);
      P.j[2] = mkj(stIn, oSTM0n, 16, memb, oSTM0m, 64, 25, R2, 192, 0, 128);
      P.j[3] = mkj(stIn, oSTM1n, 16, memb, oSTM1m, 64, 25, R2, 192, 128, 64);
      launchB(P);
    }
    st_gate1_k<<<2048, 256, 0, stream>>>(R1, R2, cs[0], memb);
    {
      Batch P; P.n = 2;
      P.j[0] = mkj(cs[0], oSTOa, 64, memb, oSTOb, 64, 25, B64a, 64, 0, 64);
      P.j[1] = mkj(cs[0], oCLa, 64, memb, oCLb, 64, 1, B64b, 64, 0, 64);
      launchB(P);
    }
    st_gate2_k<<<2048, 256, 0, stream>>>(R1, B64a, B64b, hs[0], diffb);

    for (int i = 1; i < 4; ++i) {
      int li = i - 1;
      const float* din = (i == 1) ? diffb : dh[i - 2];
      {
        // Batch A: MN (t>=1) + S + X + T  -> n = 8 (or 6 at t=0)
        Batch P; int n = 0;
        if (t >= 1) {
          P.j[n++] = mkj(dh[li], oMNa0[li], 64, din, oMNb0[li], 64, 25, R1, 256, 0, 128);
          P.j[n++] = mkj(dh[li], oMNa1[li], 64, din, oMNb1[li], 64, 25, R1, 256, 128, 128);
        }
        P.j[n++] = mkj(memb, oS0[li], 64, nullptr, oS0[li], 0, 25, R5, 256, 0, 128);
        P.j[n++] = mkj(memb, oS1[li], 64, nullptr, oS1[li], 0, 25, R5, 256, 128, 128);
        P.j[n++] = mkj(hs[i - 1], oX0[li], 64, nullptr, oX0[li], 0, 25, R3, 256, 0, 128);
        P.j[n++] = mkj(hs[i - 1], oX1[li], 64, nullptr, oX1[li], 0, 25, R3, 256, 128, 128);
        P.j[n++] = mkj(hs[i], oT0[li], 64, nullptr, oT0[li], 0, 25, R2, 192, 0, 128);
        P.j[n++] = mkj(hs[i], oT1[li], 64, nullptr, oT1[li], 0, 25, R2, 192, 128, 64);
        P.n = n;
        launchB(P);
      }
      if (t >= 1)
        mimn_gate_k<<<2048, 256, 0, stream>>>(R1, dh[li], dcb[li],
                                              mn_ctw + (size_t)li * 131072,
                                              mn_ocw + (size_t)li * 65536);
      {
        // Batch B: MH + MX -> n = 4 (MX of zeros at t=0 gives 0, correct)
        Batch P; P.n = 4;
        P.j[0] = mkj(cs[i], oMH0[li], 64, nullptr, oMH0[li], 0, 25, RM, 256, 0, 128);
        P.j[1] = mkj(cs[i], oMH1[li], 64, nullptr, oMH1[li], 0, 25, RM, 256, 128, 128);
        P.j[2] = mkj(dh[li], oMX0[li], 64, nullptr, oMX0[li], 0, 25, R1, 256, 0, 128);
        P.j[3] = mkj(dh[li], oMX1[li], 64, nullptr, oMX1[li], 0, 25, R1, 256, 128, 128);
        launchB(P);
      }
      mb_gate1_k<<<2048, 256, 0, stream>>>(R5, R2, R3, RM, R1, memb, cs[i], ccb[li],
                                           mb_ctw + (size_t)li * 131072,
                                           mb_ocw + (size_t)li * 65536);
      mb_gate2c1_k<<<128, 256, 0, stream>>>(cs[i], memb, wtmbl[li], R5, R2, R3, hs[i]);
    }
    xgen_k<<<32, 256, 0, stream>>>(hs[3], wtwl, xgen, out, t);
  }
}

// Round 9
// 15348.785 us; speedup vs baseline: 1.5293x; 1.0932x over previous
//
#include <hip/hip_runtime.h>
#include <math.h>

// ---------------------------------------------------------------------------
// MIM RNN round 8: px-split x2 (4-row blocks, 64 blocks/job -> halved
// per-launch wall time), MH hoisted into batch A (640-block launch, 2.5
// blocks/CU), CL fused into st_gate2c1. Split-bf16, depth-2 A ping-pong.
// ---------------------------------------------------------------------------

#define S 524288  // 8*64*1024

typedef __attribute__((ext_vector_type(8))) short bf16x8;
typedef __attribute__((ext_vector_type(16))) float f32x16;

__device__ __forceinline__ float sigf(float x) { return 1.0f / (1.0f + expf(-x)); }
__device__ __forceinline__ unsigned short f2bf(float f) {
  unsigned u = __float_as_uint(f);
  u += 0x7fffu + ((u >> 16) & 1u);
  return (unsigned short)(u >> 16);
}
__device__ __forceinline__ float bf2f(unsigned short h) {
  return __uint_as_float(((unsigned)h) << 16);
}

struct Job {
  const float* x0; const unsigned short* w0; int cin0;
  const float* x1; const unsigned short* w1; int cin1;
  int taps; float* out; int outCo; int coBase; int coCnt;
};
struct Batch { Job j[10]; int n; };

// ---------------------------------------------------------------------------
// Weight prepack: W'[half][tap][ks][coB4][lane64][8] bf16.
__global__ void pack_k(unsigned short* dst, const float* src, int srcRow0,
                       int nRows, int dstRow0, int ciBase, int cinSrc, int taps,
                       int KS) {
  int idx = blockIdx.x * 256 + threadIdx.x;
  int total = taps * KS * 4 * 64;
  if (idx >= total) return;
  int l = idx & 63;
  int cb = (idx >> 6) & 3;
  int rest = idx >> 8;
  int ks = rest % KS, tap = rest / KS;
  int co_d = cb * 32 + (l & 31);
  if (co_d < dstRow0 || co_d >= dstRow0 + nRows) return;
  int srcRow = srcRow0 + (co_d - dstRow0);
  size_t AH = (size_t)taps * KS * 2048;
  size_t base = ((size_t)(tap * KS + ks) * 4 + cb) * 512 + (size_t)l * 8;
#pragma unroll
  for (int j = 0; j < 8; ++j) {
    int ci = ciBase + ks * 16 + (l >> 5) * 8 + j;
    float v = src[((size_t)srcRow * cinSrc + ci) * taps + tap];
    unsigned short hi = f2bf(v);
    unsigned short lo = f2bf(v - bf2f(hi));
    dst[base + j] = hi;
    dst[AH + base + j] = lo;
  }
}

__global__ void tr1_k(const float* __restrict__ src, float* __restrict__ dst,
                      int Cin, int Cout) {
  int idx = blockIdx.x * 256 + threadIdx.x;
  if (idx >= Cout * Cin) return;
  int ci = idx % Cin, co = idx / Cin;
  dst[(size_t)ci * Cout + co] = src[idx];
}

// ---------------------------------------------------------------------------
// Conv: block = 128co x 128px (4 img rows), 4 waves = 2 wc x 2 wr; wave =
// 2 co-tiles x 2 px-row-tiles. Slice = (tap,kk): 4 A-frags + 4 B LDS reads +
// 12 MFMAs; A ping-pong prefetched 2 slices ahead. 64 blocks per job.
__global__ __launch_bounds__(256, 2) void convmf6_k(Batch bt) {
  int blk = blockIdx.x;
  int ji = blk % bt.n;
  int local = blk / bt.n;
  Job J = bt.j[ji];
  int pxg = local & 7;
  int b = local >> 3;
  int r0 = pxg * 4;
  int tid = threadIdx.x, l = tid & 63, wv = tid >> 6;
  int wc = wv & 1, wr = wv >> 1;
  int lcol = l & 31, lg = l >> 5;

  // B-tile: [half][8 rows][36 cols x 64B]; 32 ci per (row,col) in 4
  // XOR-swizzled 16B slots. Row stride 2368B. Rows = img r0-2 .. r0+5.
  __shared__ __align__(16) unsigned char lds[2][8][2368];

  f32x16 acc[2][2];
#pragma unroll
  for (int r = 0; r < 2; ++r)
#pragma unroll
    for (int j2 = 0; j2 < 2; ++j2)
#pragma unroll
      for (int q = 0; q < 16; ++q) acc[r][j2][q] = 0.f;

  {  // zero halo cols 0,1,34,35 once: 2 halves x 8 rows x 4 slots x 4 cols
    int e = tid;  // exactly 256
    int hh = e & 1, sl = (e >> 1) & 3;
    int row = (e >> 3) & 7, cx = e >> 6;
    int col = cx < 2 ? cx : 32 + cx;
    float4 z = {0.f, 0.f, 0.f, 0.f};
    *(float4*)&lds[hh][row][col * 64 + sl * 16] = z;
  }

  for (int s = 0; s < 2; ++s) {
    const float* X = s ? J.x1 : J.x0;
    const unsigned short* W = s ? J.w1 : J.w0;
    int cin = s ? J.cin1 : J.cin0;
    if (cin == 0) continue;
    int KS = cin >> 4;
    size_t AH = (size_t)J.taps * KS * 2048;
    int nst = (cin + 31) >> 5;
    for (int st = 0; st < nst; ++st) {
      int ciCnt = cin - st * 32;
      if (ciCnt > 32) ciCnt = 32;
      int kls = ciCnt >> 4;      // 1 or 2
      int kshift = kls >> 1;     // 0 or 1
      int NS = J.taps * kls;
      auto aaddr = [&](int u) {
        int tap = u >> kshift, kk = u & (kls - 1);
        return W + (((size_t)tap * KS + st * 2 + kk) * 4 + wc * 2) * 512 +
               (size_t)l * 8;
      };
      // A prologue (issued BEFORE barriers: flies under LDS staging)
      bf16x8 pah0, pah1, pal0, pal1, pbh0, pbh1, pbl0, pbl1;
      {
        const unsigned short* wp = aaddr(0);
        pah0 = *(const bf16x8*)wp;
        pah1 = *(const bf16x8*)(wp + 512);
        pal0 = *(const bf16x8*)(wp + AH);
        pal1 = *(const bf16x8*)(wp + AH + 512);
      }
      if (NS > 1) {
        const unsigned short* wp = aaddr(1);
        pbh0 = *(const bf16x8*)wp;
        pbh1 = *(const bf16x8*)(wp + 512);
        pbl0 = *(const bf16x8*)(wp + AH);
        pbl1 = *(const bf16x8*)(wp + AH + 512);
      }
      __syncthreads();
      // stage 8 rows (r0-2 .. r0+5) of up-to-32 ci, hi+lo halves
      for (int u = tid; u < 1024; u += 256) {
        int cp = u & 15;
        int xq = (u >> 4) & 7;
        int row = u >> 7;  // 0..7
        if (2 * cp < ciCnt) {
          int gy = r0 - 2 + row;
          float4 v0 = {0.f, 0.f, 0.f, 0.f}, v1 = {0.f, 0.f, 0.f, 0.f};
          if ((unsigned)gy < 32u) {
            const float* p0 =
                X + (((size_t)b * cin + st * 32 + 2 * cp) << 10) + gy * 32 + xq * 4;
            v0 = *(const float4*)p0;
            v1 = *(const float4*)(p0 + 1024);
          }
          const float* e0 = (const float*)&v0;
          const float* e1 = (const float*)&v1;
          int slot = cp >> 2, boff = (cp & 3) * 4;
#pragma unroll
          for (int e = 0; e < 4; ++e) {
            int col = xq * 4 + 2 + e;
            int off2 = col * 64 + ((slot ^ ((col >> 1) & 3)) << 4) + boff;
            unsigned short h0 = f2bf(e0[e]);
            unsigned short h1 = f2bf(e1[e]);
            unsigned short lo0 = f2bf(e0[e] - bf2f(h0));
            unsigned short lo1 = f2bf(e1[e] - bf2f(h1));
            *(unsigned*)&lds[0][row][off2] = (unsigned)h0 | ((unsigned)h1 << 16);
            *(unsigned*)&lds[1][row][off2] = (unsigned)lo0 | ((unsigned)lo1 << 16);
          }
        }
      }
      __syncthreads();
      auto slice = [&](int u, bf16x8 ah0, bf16x8 ah1, bf16x8 al0, bf16x8 al1) {
        int tap = u >> kshift, kk = u & (kls - 1);
        int dy, dx;
        if (J.taps == 1) { dy = 2; dx = 2; }
        else { dy = tap / 5; dx = tap - dy * 5; }
        int col = lcol + dx, cOff = col * 64, swz = (col >> 1) & 3;
        int phys = (((kk * 2 + lg) ^ swz) << 4);
        bf16x8 bb0 = *(const bf16x8*)&lds[0][wr * 2 + dy][cOff + phys];
        bf16x8 bb1 = *(const bf16x8*)&lds[0][wr * 2 + 1 + dy][cOff + phys];
        acc[0][0] = __builtin_amdgcn_mfma_f32_32x32x16_bf16(ah0, bb0, acc[0][0], 0, 0, 0);
        acc[1][0] = __builtin_amdgcn_mfma_f32_32x32x16_bf16(ah1, bb0, acc[1][0], 0, 0, 0);
        acc[0][1] = __builtin_amdgcn_mfma_f32_32x32x16_bf16(ah0, bb1, acc[0][1], 0, 0, 0);
        acc[1][1] = __builtin_amdgcn_mfma_f32_32x32x16_bf16(ah1, bb1, acc[1][1], 0, 0, 0);
        acc[0][0] = __builtin_amdgcn_mfma_f32_32x32x16_bf16(al0, bb0, acc[0][0], 0, 0, 0);
        acc[1][0] = __builtin_amdgcn_mfma_f32_32x32x16_bf16(al1, bb0, acc[1][0], 0, 0, 0);
        acc[0][1] = __builtin_amdgcn_mfma_f32_32x32x16_bf16(al0, bb1, acc[0][1], 0, 0, 0);
        acc[1][1] = __builtin_amdgcn_mfma_f32_32x32x16_bf16(al1, bb1, acc[1][1], 0, 0, 0);
        // lo-half of B (pass 3 = ah * bl)
        bb0 = *(const bf16x8*)(&lds[0][wr * 2 + dy][cOff + phys] + 8 * 2368);
        bb1 = *(const bf16x8*)(&lds[0][wr * 2 + 1 + dy][cOff + phys] + 8 * 2368);
        acc[0][0] = __builtin_amdgcn_mfma_f32_32x32x16_bf16(ah0, bb0, acc[0][0], 0, 0, 0);
        acc[1][0] = __builtin_amdgcn_mfma_f32_32x32x16_bf16(ah1, bb0, acc[1][0], 0, 0, 0);
        acc[0][1] = __builtin_amdgcn_mfma_f32_32x32x16_bf16(ah0, bb1, acc[0][1], 0, 0, 0);
        acc[1][1] = __builtin_amdgcn_mfma_f32_32x32x16_bf16(ah1, bb1, acc[1][1], 0, 0, 0);
      };
      for (int uu = 0; uu < NS; uu += 2) {
        slice(uu, pah0, pah1, pal0, pal1);
        if (uu + 2 < NS) {
          const unsigned short* wp = aaddr(uu + 2);
          pah0 = *(const bf16x8*)wp;
          pah1 = *(const bf16x8*)(wp + 512);
          pal0 = *(const bf16x8*)(wp + AH);
          pal1 = *(const bf16x8*)(wp + AH + 512);
        }
        if (uu + 1 < NS) {
          slice(uu + 1, pbh0, pbh1, pbl0, pbl1);
          if (uu + 3 < NS) {
            const unsigned short* wp = aaddr(uu + 3);
            pbh0 = *(const bf16x8*)wp;
            pbh1 = *(const bf16x8*)(wp + 512);
            pbl0 = *(const bf16x8*)(wp + AH);
            pbl1 = *(const bf16x8*)(wp + AH + 512);
          }
        }
      }
    }
  }
  // store: D col = lane&31 (px), row = (reg&3) + 8*(reg>>2) + 4*(lane>>5)
#pragma unroll
  for (int r = 0; r < 2; ++r) {
#pragma unroll
    for (int j2 = 0; j2 < 2; ++j2) {
      int prow = r0 + wr * 2 + j2;
      float* op = J.out + (((size_t)b * J.outCo) << 10) + prow * 32 + lcol;
#pragma unroll
      for (int q = 0; q < 16; ++q) {
        int coLoc = wc * 64 + r * 32 + 4 * lg + (q & 3) + 8 * (q >> 2);
        if (coLoc < J.coCnt)
          op[(size_t)(J.coBase + coLoc) << 10] = acc[r][j2][q];
      }
    }
  }
}

// ---------------------------------------------------------------------------
__global__ void build_net_k(const float* __restrict__ frames0, float* __restrict__ net,
                            int t) {
  int idx = blockIdx.x * 256 + threadIdx.x;
  int b = idx >> 14, ch = (idx >> 10) & 15, p = idx & 1023;
  int y = p >> 5, x = p & 31, py = ch >> 2, px = ch & 3;
  net[idx] = frames0[((size_t)b * 10 + t) * 16384 + (y * 4 + py) * 128 + (x * 4 + px)];
}

// STH [b][256]: i,f,g,o ; STM [b][192]: i',f',g'
__global__ void st_gate1_k(const float* __restrict__ sth, const float* __restrict__ stm,
                           float* __restrict__ c, float* __restrict__ m) {
  int idx = blockIdx.x * 256 + threadIdx.x;
  int b = idx >> 16, r = idx & 65535;
  const float* hb = sth + (size_t)b * 262144 + r;
  const float* mb = stm + (size_t)b * 196608 + r;
  float cn = sigf(hb[65536] + 1.f) * c[idx] + sigf(hb[0]) * tanhf(hb[131072]);
  float mn = sigf(mb[65536] + 1.f) * m[idx] + sigf(mb[0]) * tanhf(mb[131072]);
  c[idx] = cn;
  m[idx] = mn;
}

// fused: conv1(st_cl over [c,m]) + o-gate + h/diff write. grid 128
__global__ __launch_bounds__(256) void st_gate2c1_k(
    const float* __restrict__ c0, const float* __restrict__ m0,
    const float* __restrict__ wcl, const float* __restrict__ sth,
    const float* __restrict__ oS, float* __restrict__ h, float* __restrict__ diff) {
  int blk = blockIdx.x;
  int coB = blk & 3, pb = (blk >> 2) & 3, b = blk >> 4;
  int tid = threadIdx.x, px = pb * 256 + tid;
  float acc[16];
#pragma unroll
  for (int c = 0; c < 16; ++c) acc[c] = 0.f;
  const float* ib1 = c0 + (size_t)b * 65536 + px;
  const float* ib2 = m0 + (size_t)b * 65536 + px;
  for (int ci = 0; ci < 64; ++ci) {
    float v1 = ib1[ci * 1024], v2 = ib2[ci * 1024];
    const float* w1 = wcl + (size_t)ci * 64 + coB * 16;
    const float* w2 = wcl + (size_t)(64 + ci) * 64 + coB * 16;
#pragma unroll
    for (int c = 0; c < 16; ++c) {
      acc[c] = fmaf(w1[c], v1, acc[c]);
      acc[c] = fmaf(w2[c], v2, acc[c]);
    }
  }
#pragma unroll
  for (int c = 0; c < 16; ++c) {
    int co = coB * 16 + c;
    size_t o = (size_t)co * 1024 + px;
    float sto = sth[(size_t)b * 262144 + 196608 + o];
    float hn = sigf(sto + oS[(size_t)b * 65536 + o]) * tanhf(acc[c]);
    size_t ho = (size_t)b * 65536 + o;
    float old = h[ho];
    h[ho] = hn;
    diff[ho] = hn - old;
  }
}

// merged MN conv output: chunks i,g,f,o
__global__ void mimn_gate_k(const float* __restrict__ MN, float* __restrict__ dh,
                            float* __restrict__ dc, const float* __restrict__ ctw,
                            const float* __restrict__ ocw) {
  int idx = blockIdx.x * 256 + threadIdx.x;
  int b = idx >> 16, r = idx & 65535;
  const float* q = MN + (size_t)b * 262144 + r;
  float c0 = dc[idx];
  float cn = sigf(q[131072] + c0 * ctw[65536 + r] + 1.f) * c0 +
             sigf(q[0] + c0 * ctw[r]) * tanhf(q[65536]);
  float hn = sigf(q[196608] + cn * ocw[r]) * tanhf(cn);
  dc[idx] = cn;
  dh[idx] = hn;
}

// S:i,g,f,o  T:i,g,o  X:i,g,f,o  QH/QX:i,g,f,o (summed)
__global__ void mb_gate1_k(const float* __restrict__ Sb, const float* __restrict__ Tb,
                           const float* __restrict__ Xb, const float* __restrict__ QH,
                           const float* __restrict__ QX, float* __restrict__ m,
                           float* __restrict__ c, float* __restrict__ cc,
                           const float* __restrict__ ctw, const float* __restrict__ ocw) {
  int idx = blockIdx.x * 256 + threadIdx.x;
  int b = idx >> 16, r = idx & 65535;
  const float* sb = Sb + (size_t)b * 262144 + r;
  const float* tb = Tb + (size_t)b * 196608 + r;
  const float* xb = Xb + (size_t)b * 262144 + r;
  const float* qh = QH + (size_t)b * 262144 + r;
  const float* qx = QX + (size_t)b * 262144 + r;
  float i_s = sb[0], g_s = sb[65536], f_s = sb[131072];
  float i_t = tb[0], g_t = tb[65536];
  float i_x = xb[0], g_x = xb[65536], f_x = xb[131072];
  float m0 = m[idx];
  float nm = sigf(f_x + f_s + 1.f) * m0 + sigf(i_x + i_s) * tanhf(g_x + g_s);
  float q_i = qh[0] + qx[0], q_g = qh[65536] + qx[65536];
  float q_f = qh[131072] + qx[131072], q_o = qh[196608] + qx[196608];
  float cc0 = cc[idx];
  float mims = sigf(q_f + cc0 * ctw[65536 + r] + 1.f) * cc0 +
               sigf(q_i + cc0 * ctw[r]) * tanhf(q_g);
  float h2 = sigf(q_o + mims * ocw[r]) * tanhf(mims);
  float nc = h2 + sigf(i_x + i_t) * tanhf(g_x + g_t);
  m[idx] = nm;
  c[idx] = nc;
  cc[idx] = mims;
}

// fused conv1(mb_last over [cI,m0]) + 3-term output gate. grid 128
__global__ __launch_bounds__(256) void mb_gate2c1_k(
    const float* __restrict__ cI, const float* __restrict__ m0,
    const float* __restrict__ wl, const float* __restrict__ Sb,
    const float* __restrict__ Tb, const float* __restrict__ Xb,
    float* __restrict__ h) {
  int blk = blockIdx.x;
  int coB = blk & 3, pb = (blk >> 2) & 3, b = blk >> 4;
  int tid = threadIdx.x, px = pb * 256 + tid;
  float acc[16];
#pragma unroll
  for (int c = 0; c < 16; ++c) acc[c] = 0.f;
  const float* ib1 = cI + (size_t)b * 65536 + px;
  const float* ib2 = m0 + (size_t)b * 65536 + px;
  for (int ci = 0; ci < 64; ++ci) {
    float v1 = ib1[ci * 1024], v2 = ib2[ci * 1024];
    const float* w1 = wl + (size_t)ci * 64 + coB * 16;
    const float* w2 = wl + (size_t)(64 + ci) * 64 + coB * 16;
#pragma unroll
    for (int c = 0; c < 16; ++c) {
      acc[c] = fmaf(w1[c], v1, acc[c]);
      acc[c] = fmaf(w2[c], v2, acc[c]);
    }
  }
#pragma unroll
  for (int c = 0; c < 16; ++c) {
    int co = coB * 16 + c;
    size_t o = (size_t)co * 1024 + px;
    float osum = Xb[(size_t)b * 262144 + 196608 + o] +
                 Tb[(size_t)b * 196608 + 131072 + o] +
                 Sb[(size_t)b * 262144 + 196608 + o];
    h[(size_t)b * 65536 + o] = sigf(osum) * tanhf(acc[c]);
  }
}

// final conv1 w_last + unpatchify. grid 32
__global__ __launch_bounds__(256) void xgen_k(const float* __restrict__ h3,
                                              const float* __restrict__ wwl,
                                              float* __restrict__ xg,
                                              float* __restrict__ out, int t) {
  int blk = blockIdx.x;
  int pb = blk & 3, b = blk >> 2;
  int tid = threadIdx.x, px = pb * 256 + tid;
  float acc[16];
#pragma unroll
  for (int c = 0; c < 16; ++c) acc[c] = 0.f;
  const float* ib = h3 + (size_t)b * 65536 + px;
  for (int ci = 0; ci < 64; ++ci) {
    float v = ib[ci * 1024];
    const float* w = wwl + (size_t)ci * 16;
#pragma unroll
    for (int c = 0; c < 16; ++c) acc[c] = fmaf(w[c], v, acc[c]);
  }
  int y = px >> 5, x = px & 31;
#pragma unroll
  for (int c = 0; c < 16; ++c) {
    xg[(size_t)b * 16384 + (size_t)c * 1024 + px] = acc[c];
    if (t >= 9) {
      int py = c >> 2, pxs = c & 3;
      out[((size_t)b * 10 + (t - 9)) * 16384 + (y * 4 + py) * 128 + (x * 4 + pxs)] =
          acc[c];
    }
  }
}

// ---------------------------------------------------------------------------
extern "C" void kernel_launch(void* const* d_in, const int* in_sizes, int n_in,
                              void* d_out, int out_size, void* d_ws, size_t ws_size,
                              hipStream_t stream) {
  const float* frames0 = (const float*)d_in[0];
  const float* st_cx = (const float*)d_in[2];
  const float* st_ch = (const float*)d_in[3];
  const float* st_cm = (const float*)d_in[4];
  const float* st_co = (const float*)d_in[5];
  const float* st_cl = (const float*)d_in[6];
  const float* mb_t = (const float*)d_in[7];
  const float* mb_s = (const float*)d_in[8];
  const float* mb_x = (const float*)d_in[9];
  const float* mb_mh = (const float*)d_in[10];
  const float* mb_mx = (const float*)d_in[11];
  const float* mb_ctw = (const float*)d_in[12];
  const float* mb_ocw = (const float*)d_in[13];
  const float* mb_last = (const float*)d_in[14];
  const float* mn_ch = (const float*)d_in[15];
  const float* mn_cx = (const float*)d_in[16];
  const float* mn_ctw = (const float*)d_in[17];
  const float* mn_ocw = (const float*)d_in[18];
  const float* w_last = (const float*)d_in[19];
  float* out = (float*)d_out;

  float* ws = (float*)d_ws;
  size_t off = 0;
  auto A_ = [&](size_t n) { float* p = ws + off; off += n; return p; };
  float* hs[4]; for (int i = 0; i < 4; ++i) hs[i] = A_(S);
  float* cs[4]; for (int i = 0; i < 4; ++i) cs[i] = A_(S);
  float* memb = A_(S);
  float* dh[3]; for (int i = 0; i < 3; ++i) dh[i] = A_(S);
  float* dcb[3]; for (int i = 0; i < 3; ++i) dcb[i] = A_(S);
  float* ccb[3]; for (int i = 0; i < 3; ++i) ccb[i] = A_(S);
  float* diffb = A_(S);
  size_t zeroFloats = off;  // 19*S
  float* xgen = A_(131072);
  float* netb = A_(131072);
  float* R1 = A_(4 * S);   // STH / MN / QX
  float* R2 = A_(3 * S);   // STM / T
  float* R3 = A_(4 * S);   // X
  float* R5 = A_(4 * S);   // S
  float* RM = A_(4 * S);   // MH (QH)
  float* B64a = A_(S);     // STO
  float* wtmbl[3]; for (int li = 0; li < 3; ++li) wtmbl[li] = A_(8192);
  float* wtcl = A_(8192);
  float* wtwl = A_(1024);
  unsigned short* warena = (unsigned short*)(ws + off);

  size_t wOff = 0;
  auto alloc = [&](int taps, int KS) {
    size_t o = wOff;
    wOff += (size_t)2 * taps * KS * 2048;
    return o;
  };
  size_t oSTH0n = alloc(25, 1), oSTH0h = alloc(25, 4);
  size_t oSTH1n = alloc(25, 1), oSTH1h = alloc(25, 4);
  size_t oSTM0n = alloc(25, 1), oSTM0m = alloc(25, 4);
  size_t oSTM1n = alloc(25, 1), oSTM1m = alloc(25, 4);
  size_t oSTOa = alloc(25, 4), oSTOb = alloc(25, 4);
  size_t oMNa0[3], oMNa1[3], oMNb0[3], oMNb1[3], oS0[3], oS1[3], oT0[3], oT1[3],
      oX0[3], oX1[3], oMH0[3], oMH1[3], oMX0[3], oMX1[3];
  for (int li = 0; li < 3; ++li) {
    oMNa0[li] = alloc(25, 4); oMNa1[li] = alloc(25, 4);
    oMNb0[li] = alloc(25, 4); oMNb1[li] = alloc(25, 4);
    oS0[li] = alloc(25, 4); oS1[li] = alloc(25, 4);
    oT0[li] = alloc(25, 4); oT1[li] = alloc(25, 4);
    oX0[li] = alloc(25, 4); oX1[li] = alloc(25, 4);
    oMH0[li] = alloc(25, 4); oMH1[li] = alloc(25, 4);
    oMX0[li] = alloc(25, 4); oMX1[li] = alloc(25, 4);
  }
  if (ws_size < off * sizeof(float) + wOff * sizeof(unsigned short)) return;

  hipMemsetAsync(ws, 0, zeroFloats * sizeof(float), stream);
  hipMemsetAsync(warena, 0, wOff * sizeof(unsigned short), stream);

  auto packL = [&](size_t dstOff, const float* src, int srcRow0, int nRows,
                   int dstRow0, int ciBase, int cinSrc, int taps, int KS) {
    int total = taps * KS * 4 * 64;
    pack_k<<<(total + 255) / 256, 256, 0, stream>>>(warena + dstOff, src, srcRow0,
                                                    nRows, dstRow0, ciBase, cinSrc,
                                                    taps, KS);
  };
  // st_cx rows: i(0) f(64) g(128) i'(192) f'(256) g'(320) o(384)
  packL(oSTH0n, st_cx, 0, 128, 0, 0, 16, 25, 1);
  packL(oSTH0h, st_ch, 0, 128, 0, 0, 64, 25, 4);
  packL(oSTH1n, st_cx, 128, 64, 0, 0, 16, 25, 1);
  packL(oSTH1n, st_cx, 384, 64, 64, 0, 16, 25, 1);
  packL(oSTH1h, st_ch, 128, 128, 0, 0, 64, 25, 4);
  packL(oSTM0n, st_cx, 192, 128, 0, 0, 16, 25, 1);
  packL(oSTM0m, st_cm, 0, 128, 0, 0, 64, 25, 4);
  packL(oSTM1n, st_cx, 320, 64, 0, 0, 16, 25, 1);
  packL(oSTM1m, st_cm, 128, 64, 0, 0, 64, 25, 4);
  packL(oSTOa, st_co, 0, 64, 0, 0, 128, 25, 4);
  packL(oSTOb, st_co, 0, 64, 0, 64, 128, 25, 4);
  for (int li = 0; li < 3; ++li) {
    const float* ch = mn_ch + (size_t)li * 409600;
    const float* cx = mn_cx + (size_t)li * 409600;
    const float* mbs = mb_s + (size_t)li * 409600;
    const float* mbt = mb_t + (size_t)li * 307200;
    const float* mbx = mb_x + (size_t)li * 409600;
    const float* mmh = mb_mh + (size_t)li * 409600;
    const float* mmx = mb_mx + (size_t)li * 409600;
    packL(oMNa0[li], ch, 0, 128, 0, 0, 64, 25, 4);
    packL(oMNa1[li], ch, 128, 128, 0, 0, 64, 25, 4);
    packL(oMNb0[li], cx, 0, 128, 0, 0, 64, 25, 4);
    packL(oMNb1[li], cx, 128, 128, 0, 0, 64, 25, 4);
    packL(oS0[li], mbs, 0, 128, 0, 0, 64, 25, 4);
    packL(oS1[li], mbs, 128, 128, 0, 0, 64, 25, 4);
    packL(oT0[li], mbt, 0, 128, 0, 0, 64, 25, 4);
    packL(oT1[li], mbt, 128, 64, 0, 0, 64, 25, 4);
    packL(oX0[li], mbx, 0, 128, 0, 0, 64, 25, 4);
    packL(oX1[li], mbx, 128, 128, 0, 0, 64, 25, 4);
    packL(oMH0[li], mmh, 0, 128, 0, 0, 64, 25, 4);
    packL(oMH1[li], mmh, 128, 128, 0, 0, 64, 25, 4);
    packL(oMX0[li], mmx, 0, 128, 0, 0, 64, 25, 4);
    packL(oMX1[li], mmx, 128, 128, 0, 0, 64, 25, 4);
    tr1_k<<<32, 256, 0, stream>>>(mb_last + (size_t)li * 8192, wtmbl[li], 128, 64);
  }
  tr1_k<<<32, 256, 0, stream>>>(st_cl, wtcl, 128, 64);
  tr1_k<<<4, 256, 0, stream>>>(w_last, wtwl, 64, 16);

  auto mkj = [&](const float* x0, size_t w0, int cin0, const float* x1, size_t w1,
                 int cin1, int taps, float* o, int outCo, int coBase, int coCnt) {
    Job j;
    j.x0 = x0; j.w0 = warena + w0; j.cin0 = cin0;
    j.x1 = x1; j.w1 = warena + w1; j.cin1 = cin1;
    j.taps = taps; j.out = o; j.outCo = outCo; j.coBase = coBase; j.coCnt = coCnt;
    return j;
  };
  auto launchB = [&](Batch& bt) {
    convmf6_k<<<bt.n * 64, 256, 0, stream>>>(bt);
  };

  for (int t = 0; t < 19; ++t) {
    const float* stIn = (t < 10) ? netb : xgen;
    if (t < 10) build_net_k<<<512, 256, 0, stream>>>(frames0, netb, t);
    {
      Batch P; P.n = 4;
      P.j[0] = mkj(stIn, oSTH0n, 16, hs[0], oSTH0h, 64, 25, R1, 256, 0, 128);
      P.j[1] = mkj(stIn, oSTH1n, 16, hs[0], oSTH1h, 64, 25, R1, 256, 128, 128);
      P.j[2] = mkj(stIn, oSTM0n, 16, memb, oSTM0m, 64, 25, R2, 192, 0, 128);
      P.j[3] = mkj(stIn, oSTM1n, 16, memb, oSTM1m, 64, 25, R2, 192, 128, 64);
      launchB(P);
    }
    st_gate1_k<<<2048, 256, 0, stream>>>(R1, R2, cs[0], memb);
    {
      Batch P; P.n = 1;
      P.j[0] = mkj(cs[0], oSTOa, 64, memb, oSTOb, 64, 25, B64a, 64, 0, 64);
      launchB(P);
    }
    st_gate2c1_k<<<128, 256, 0, stream>>>(cs[0], memb, wtcl, R1, B64a, hs[0], diffb);

    for (int i = 1; i < 4; ++i) {
      int li = i - 1;
      const float* din = (i == 1) ? diffb : dh[i - 2];
      {
        // Batch A: MN (t>=1) + S + X + T + MH  -> n = 10 (8 at t=0)
        Batch P; int n = 0;
        if (t >= 1) {
          P.j[n++] = mkj(dh[li], oMNa0[li], 64, din, oMNb0[li], 64, 25, R1, 256, 0, 128);
          P.j[n++] = mkj(dh[li], oMNa1[li], 64, din, oMNb1[li], 64, 25, R1, 256, 128, 128);
        }
        P.j[n++] = mkj(memb, oS0[li], 64, nullptr, oS0[li], 0, 25, R5, 256, 0, 128);
        P.j[n++] = mkj(memb, oS1[li], 64, nullptr, oS1[li], 0, 25, R5, 256, 128, 128);
        P.j[n++] = mkj(hs[i - 1], oX0[li], 64, nullptr, oX0[li], 0, 25, R3, 256, 0, 128);
        P.j[n++] = mkj(hs[i - 1], oX1[li], 64, nullptr, oX1[li], 0, 25, R3, 256, 128, 128);
        P.j[n++] = mkj(hs[i], oT0[li], 64, nullptr, oT0[li], 0, 25, R2, 192, 0, 128);
        P.j[n++] = mkj(hs[i], oT1[li], 64, nullptr, oT1[li], 0, 25, R2, 192, 128, 64);
        P.j[n++] = mkj(cs[i], oMH0[li], 64, nullptr, oMH0[li], 0, 25, RM, 256, 0, 128);
        P.j[n++] = mkj(cs[i], oMH1[li], 64, nullptr, oMH1[li], 0, 25, RM, 256, 128, 128);
        P.n = n;
        launchB(P);
      }
      if (t >= 1)
        mimn_gate_k<<<2048, 256, 0, stream>>>(R1, dh[li], dcb[li],
                                              mn_ctw + (size_t)li * 131072,
                                              mn_ocw + (size_t)li * 65536);
      {
        // Batch B: MX (dh post-update; zeros at t=0 -> writes zeros, correct)
        Batch P; P.n = 2;
        P.j[0] = mkj(dh[li], oMX0[li], 64, nullptr, oMX0[li], 0, 25, R1, 256, 0, 128);
        P.j[1] = mkj(dh[li], oMX1[li], 64, nullptr, oMX1[li], 0, 25, R1, 256, 128, 128);
        launchB(P);
      }
      mb_gate1_k<<<2048, 256, 0, stream>>>(R5, R2, R3, RM, R1, memb, cs[i], ccb[li],
                                           mb_ctw + (size_t)li * 131072,
                                           mb_ocw + (size_t)li * 65536);
      mb_gate2c1_k<<<128, 256, 0, stream>>>(cs[i], memb, wtmbl[li], R5, R2, R3, hs[i]);
    }
    xgen_k<<<32, 256, 0, stream>>>(hs[3], wtwl, xgen, out, t);
  }
}